// Round 1
// baseline (773.086 us; speedup 1.0000x reference)
//
#include <hip/hip_runtime.h>
#include <hip/hip_bf16.h>
#include <math.h>

#define NP 50000
#define F 128
#define H 256
#define E_PPI 800000
#define ET (E_PPI + NP)   // edges + self loops
#define NPAIR 200000

// ---------------- CSR build ----------------

__global__ void deg_kernel(const int* __restrict__ dst_idx, int* __restrict__ deg) {
  int k = blockIdx.x * blockDim.x + threadIdx.x;
  if (k >= ET) return;
  int d = (k < E_PPI) ? dst_idx[k] : (k - E_PPI);
  atomicAdd(&deg[d], 1);
}

__global__ void scan_kernel(const int* __restrict__ deg, int* __restrict__ row_ptr) {
  __shared__ int buf[1024];
  __shared__ int carry_s;
  int tid = threadIdx.x;
  if (tid == 0) carry_s = 0;
  __syncthreads();
  const int n = NP + 1;
  for (int base = 0; base < n; base += 1024) {
    int idx = base + tid;
    int v = (idx < n) ? deg[idx] : 0;   // deg[NP] is 0 (memset, never incremented)
    buf[tid] = v;
    __syncthreads();
    for (int off = 1; off < 1024; off <<= 1) {
      int t = (tid >= off) ? buf[tid - off] : 0;
      __syncthreads();
      buf[tid] += t;
      __syncthreads();
    }
    if (idx < n) row_ptr[idx] = carry_s + buf[tid] - v;  // exclusive scan
    __syncthreads();
    if (tid == 0) carry_s += buf[1023];
    __syncthreads();
  }
}

__global__ void cursor_init(const int* __restrict__ row_ptr, int* __restrict__ cursor) {
  int i = blockIdx.x * blockDim.x + threadIdx.x;
  if (i < NP) cursor[i] = row_ptr[i];
}

__global__ void fill_kernel(const int* __restrict__ dst_idx, int* __restrict__ cursor,
                            int* __restrict__ col) {
  int k = blockIdx.x * blockDim.x + threadIdx.x;
  if (k >= ET) return;
  int d = (k < E_PPI) ? dst_idx[k] : (k - E_PPI);
  int pos = atomicAdd(&cursor[d], 1);
  col[pos] = k;
}

// ---------------- f32 GEMM: C[M,N] = A[M,K] @ B[K,N] ----------------
// BM=64, BN=128, BK=16, thread tile 4x8, 256 threads. K % 16 == 0, N % 128 == 0.

template<int BK>
__launch_bounds__(256)
__global__ void gemm_f32(const float* __restrict__ A, const float* __restrict__ B,
                         float* __restrict__ C, int M, int K, int N) {
  constexpr int BM = 64, BN = 128, TM = 4, TN = 8;
  __shared__ float As[BK][BM + 4];
  __shared__ float Bs[BK][BN];
  int tid = threadIdx.x;
  int tx = tid & 15;   // col group: 16 * 8 = 128 cols
  int ty = tid >> 4;   // row group: 16 * 4 = 64 rows
  int m0 = blockIdx.x * BM;
  int n0 = blockIdx.y * BN;

  float acc[TM][TN];
#pragma unroll
  for (int r = 0; r < TM; ++r)
#pragma unroll
    for (int c = 0; c < TN; ++c) acc[r][c] = 0.f;

  for (int k0 = 0; k0 < K; k0 += BK) {
    // stage A tile (BM x BK), transposed into LDS: one float4 (along k) per thread
    {
      int m = tid >> 2;
      int kv = (tid & 3) * 4;
      float4 a = make_float4(0.f, 0.f, 0.f, 0.f);
      if (m0 + m < M)
        a = *(const float4*)(A + (size_t)(m0 + m) * K + k0 + kv);
      As[kv + 0][m] = a.x; As[kv + 1][m] = a.y;
      As[kv + 2][m] = a.z; As[kv + 3][m] = a.w;
    }
    // stage B tile (BK x BN): 2 float4 per thread
#pragma unroll
    for (int i = 0; i < 2; ++i) {
      int idx = tid + i * 256;     // 0..511
      int nv = (idx & 31) * 4;     // 0..124
      int k  = idx >> 5;           // 0..15
      *(float4*)&Bs[k][nv] = *(const float4*)(B + (size_t)(k0 + k) * N + n0 + nv);
    }
    __syncthreads();
#pragma unroll
    for (int k = 0; k < BK; ++k) {
      float4 av = *(const float4*)&As[k][ty * TM];
      float4 b0 = *(const float4*)&Bs[k][tx * TN];
      float4 b1 = *(const float4*)&Bs[k][tx * TN + 4];
      float a_[4] = {av.x, av.y, av.z, av.w};
      float b_[8] = {b0.x, b0.y, b0.z, b0.w, b1.x, b1.y, b1.z, b1.w};
#pragma unroll
      for (int r = 0; r < TM; ++r)
#pragma unroll
        for (int c = 0; c < TN; ++c) acc[r][c] = fmaf(a_[r], b_[c], acc[r][c]);
    }
    __syncthreads();
  }
#pragma unroll
  for (int r = 0; r < TM; ++r) {
    int m = m0 + ty * TM + r;
    if (m < M) {
      float4 o0 = make_float4(acc[r][0], acc[r][1], acc[r][2], acc[r][3]);
      float4 o1 = make_float4(acc[r][4], acc[r][5], acc[r][6], acc[r][7]);
      *(float4*)(C + (size_t)m * N + n0 + tx * TN)     = o0;
      *(float4*)(C + (size_t)m * N + n0 + tx * TN + 4) = o1;
    }
  }
}

// ---------------- attention scalars: s[i] = h_i . a_src, d[i] = h_i . a_dst ----------------

template<int C>
__global__ void row_dots(const float* __restrict__ h, const float* __restrict__ a_s,
                         const float* __restrict__ a_d, float* __restrict__ sb,
                         float* __restrict__ db) {
  int gid = blockIdx.x * blockDim.x + threadIdx.x;
  int wave = gid >> 6, lane = gid & 63;
  if (wave >= NP) return;
  const float* row = h + (size_t)wave * C;
  float su = 0.f, dv = 0.f;
#pragma unroll
  for (int j = 0; j < C / 64; ++j) {
    float x = row[lane + j * 64];
    su = fmaf(x, a_s[lane + j * 64], su);
    dv = fmaf(x, a_d[lane + j * 64], dv);
  }
  for (int off = 32; off > 0; off >>= 1) {
    su += __shfl_xor(su, off);
    dv += __shfl_xor(dv, off);
  }
  if (lane == 0) { sb[wave] = su; db[wave] = dv; }
}

// ---------------- per-edge logits ----------------

__global__ void edge_e(const int* __restrict__ src_idx, const int* __restrict__ dst_idx,
                       const float* __restrict__ sb, const float* __restrict__ db,
                       float* __restrict__ e_buf) {
  int k = blockIdx.x * blockDim.x + threadIdx.x;
  if (k >= ET) return;
  int s, d;
  if (k < E_PPI) { s = src_idx[k]; d = dst_idx[k]; }
  else           { s = d = k - E_PPI; }
  float x = sb[s] + db[d];
  e_buf[k] = (x > 0.f) ? x : 0.2f * x;   // leaky_relu 0.2
}

// ---------------- per-dst softmax stats ----------------

__global__ void mden_kernel(const float* __restrict__ e_buf, const int* __restrict__ row_ptr,
                            const int* __restrict__ col, float* __restrict__ mmax,
                            float* __restrict__ invd) {
  int i = blockIdx.x * blockDim.x + threadIdx.x;
  if (i >= NP) return;
  int s = row_ptr[i], e = row_ptr[i + 1];
  float m = -1e30f;
  for (int j = s; j < e; ++j) m = fmaxf(m, e_buf[col[j]]);
  float sum = 0.f;
  for (int j = s; j < e; ++j) sum += __expf(e_buf[col[j]] - m);
  mmax[i] = m;
  invd[i] = 1.0f / sum;   // degree >= 1 (self loop), never 0
}

// ---------------- weighted aggregation: out[dst] = sum alpha * h[src] (+bias, relu?) ----------------

template<int C, bool RELU>
__launch_bounds__(256)
__global__ void agg_kernel(const float* __restrict__ h, const int* __restrict__ src_idx,
                           const float* __restrict__ e_buf, const float* __restrict__ mmax,
                           const float* __restrict__ invd, const int* __restrict__ row_ptr,
                           const int* __restrict__ col, const float* __restrict__ bias,
                           float* __restrict__ out) {
  int gid = blockIdx.x * blockDim.x + threadIdx.x;
  int dst = gid >> 6, lane = gid & 63;
  if (dst >= NP) return;
  constexpr int V = C / 64;
  float acc[V];
#pragma unroll
  for (int v = 0; v < V; ++v) acc[v] = 0.f;
  float m = mmax[dst], inv = invd[dst];
  int s = row_ptr[dst], e = row_ptr[dst + 1];
  for (int j = s; j < e; ++j) {
    int k = col[j];
    int src = (k < E_PPI) ? src_idx[k] : (k - E_PPI);
    float w = __expf(e_buf[k] - m) * inv;
    const float* hr = h + (size_t)src * C + lane * V;
    if constexpr (V == 4) {
      float4 x = *(const float4*)hr;
      acc[0] = fmaf(w, x.x, acc[0]); acc[1] = fmaf(w, x.y, acc[1]);
      acc[2] = fmaf(w, x.z, acc[2]); acc[3] = fmaf(w, x.w, acc[3]);
    } else {
      float2 x = *(const float2*)hr;
      acc[0] = fmaf(w, x.x, acc[0]); acc[1] = fmaf(w, x.y, acc[1]);
    }
  }
  float* o = out + (size_t)dst * C + lane * V;
#pragma unroll
  for (int v = 0; v < V; ++v) {
    float val = acc[v] + bias[lane * V + v];
    if (RELU) val = fmaxf(val, 0.f);
    o[v] = val;
  }
}

// ---------------- head: u[i] = hp2_i . Wout[:128], v[i] = hp2_i . Wout[128:] ----------------

__global__ void uv_kernel(const float* __restrict__ hp2, const float* __restrict__ Wout,
                          float* __restrict__ u, float* __restrict__ v) {
  int gid = blockIdx.x * blockDim.x + threadIdx.x;
  int wave = gid >> 6, lane = gid & 63;
  if (wave >= NP) return;
  const float* row = hp2 + (size_t)wave * 128;
  float x0 = row[lane], x1 = row[lane + 64];
  float su = fmaf(x0, Wout[lane], x1 * Wout[lane + 64]);
  float sv = fmaf(x0, Wout[128 + lane], x1 * Wout[192 + lane]);
  for (int off = 32; off > 0; off >>= 1) {
    su += __shfl_xor(su, off);
    sv += __shfl_xor(sv, off);
  }
  if (lane == 0) { u[wave] = su; v[wave] = sv; }
}

__global__ void out_kernel(const int* __restrict__ mask, const float* __restrict__ u,
                           const float* __restrict__ v, const float* __restrict__ bout,
                           float* __restrict__ out) {
  int p = blockIdx.x * blockDim.x + threadIdx.x;
  if (p >= NPAIR) return;
  int a = mask[2 * p], b = mask[2 * p + 1];
  float logit = u[a] + v[b] + bout[0];
  out[p] = 1.0f / (1.0f + __expf(-logit));
}

// ---------------- launch ----------------

extern "C" void kernel_launch(void* const* d_in, const int* in_sizes, int n_in,
                              void* d_out, int out_size, void* d_ws, size_t ws_size,
                              hipStream_t stream) {
  const float* xp   = (const float*)d_in[0];
  const int*   ei   = (const int*)d_in[5];          // ei_ppi (2, E_PPI)
  const int*   mask = (const int*)d_in[6];
  const float* Wa2  = (const float*)d_in[7]  + 2 * F * H;   // Wa[2]
  const float* asa  = (const float*)d_in[8]  + 2 * H;
  const float* ada  = (const float*)d_in[9]  + 2 * H;
  const float* ba   = (const float*)d_in[10] + 2 * H;
  const float* Wb2  = (const float*)d_in[11] + 2 * H * F;   // Wb[2]
  const float* asb  = (const float*)d_in[12] + 2 * F;
  const float* adb  = (const float*)d_in[13] + 2 * F;
  const float* bb   = (const float*)d_in[14] + 2 * F;
  const float* Wout = (const float*)d_in[21];
  const float* bout = (const float*)d_in[22];
  float* out = (float*)d_out;

  // workspace layout (256B-aligned slices)
  char* ws = (char*)d_ws;
  size_t off = 0;
  auto alloc = [&](size_t bytes) {
    void* p = ws + off;
    off = (off + bytes + 255) & ~(size_t)255;
    return p;
  };
  float* h1      = (float*)alloc((size_t)NP * H * 4);  // layer-a hidden; reused as h2
  float* hp      = (float*)alloc((size_t)NP * H * 4);  // relu'd layer-a out; reused as hp2
  float* e_buf   = (float*)alloc((size_t)ET * 4);
  int*   col     = (int*)alloc((size_t)ET * 4);
  int*   row_ptr = (int*)alloc((size_t)(NP + 1) * 4);
  int*   cursor  = (int*)alloc((size_t)NP * 4);
  int*   deg     = (int*)alloc((size_t)(NP + 1) * 4);
  float* sb      = (float*)alloc((size_t)NP * 4);
  float* db      = (float*)alloc((size_t)NP * 4);
  float* mmax    = (float*)alloc((size_t)NP * 4);
  float* invd    = (float*)alloc((size_t)NP * 4);
  float* u       = (float*)alloc((size_t)NP * 4);
  float* v       = (float*)alloc((size_t)NP * 4);

  const int* src_idx = ei;
  const int* dst_idx = ei + E_PPI;

  // CSR over ppi edges + self loops (shared by both layers)
  hipMemsetAsync(deg, 0, (size_t)(NP + 1) * 4, stream);
  deg_kernel<<<(ET + 255) / 256, 256, 0, stream>>>(dst_idx, deg);
  scan_kernel<<<1, 1024, 0, stream>>>(deg, row_ptr);
  cursor_init<<<(NP + 255) / 256, 256, 0, stream>>>(row_ptr, cursor);
  fill_kernel<<<(ET + 255) / 256, 256, 0, stream>>>(dst_idx, cursor, col);

  const int WPB = 4;                       // waves per 256-thread block
  int node_wave_blocks = (NP + WPB - 1) / WPB;

  // ---- layer a (C = 256), GAT over ppi, then relu ----
  dim3 ga((NP + 63) / 64, H / 128);
  gemm_f32<16><<<ga, 256, 0, stream>>>(xp, Wa2, h1, NP, F, H);
  row_dots<H><<<node_wave_blocks, 256, 0, stream>>>(h1, asa, ada, sb, db);
  edge_e<<<(ET + 255) / 256, 256, 0, stream>>>(src_idx, dst_idx, sb, db, e_buf);
  mden_kernel<<<(NP + 255) / 256, 256, 0, stream>>>(e_buf, row_ptr, col, mmax, invd);
  agg_kernel<H, true><<<node_wave_blocks, 256, 0, stream>>>(
      h1, src_idx, e_buf, mmax, invd, row_ptr, col, ba, hp);

  // ---- layer b (C = 128), GAT over ppi, no relu ----
  float* h2 = h1;   // reuse
  dim3 gb((NP + 63) / 64, F / 128);
  gemm_f32<16><<<gb, 256, 0, stream>>>(hp, Wb2, h2, NP, H, F);
  row_dots<F><<<node_wave_blocks, 256, 0, stream>>>(h2, asb, adb, sb, db);
  edge_e<<<(ET + 255) / 256, 256, 0, stream>>>(src_idx, dst_idx, sb, db, e_buf);
  mden_kernel<<<(NP + 255) / 256, 256, 0, stream>>>(e_buf, row_ptr, col, mmax, invd);
  float* hp2 = hp;  // reuse (gemm_b already consumed hp)
  agg_kernel<F, false><<<node_wave_blocks, 256, 0, stream>>>(
      h2, src_idx, e_buf, mmax, invd, row_ptr, col, bb, hp2);

  // ---- link-prediction head ----
  uv_kernel<<<node_wave_blocks, 256, 0, stream>>>(hp2, Wout, u, v);
  out_kernel<<<(NPAIR + 255) / 256, 256, 0, stream>>>(mask, u, v, bout, out);
}

// Round 2
// 576.962 us; speedup vs baseline: 1.3399x; 1.3399x over previous
//
#include <hip/hip_runtime.h>
#include <hip/hip_bf16.h>
#include <math.h>

#define NP 50000
#define F 128
#define H 256
#define E_PPI 800000
#define ET (E_PPI + NP)   // edges + self loops
#define NPAIR 200000

typedef __attribute__((ext_vector_type(8))) short short8v;
typedef __attribute__((ext_vector_type(4))) short short4v;
typedef __attribute__((ext_vector_type(2))) short short2v;
typedef __attribute__((ext_vector_type(4))) float float4v;

__device__ __forceinline__ short f2bs(float f) {  // f32 -> bf16 bits, RNE
  unsigned u = __builtin_bit_cast(unsigned, f);
  unsigned r = (u + 0x7FFFu + ((u >> 16) & 1u)) >> 16;
  return (short)r;
}
__device__ __forceinline__ float bs2f(short s) {
  unsigned u = ((unsigned)(unsigned short)s) << 16;
  return __builtin_bit_cast(float, u);
}

// ---------------- CSR build ----------------

__global__ void deg_kernel(const int* __restrict__ dst_idx, int* __restrict__ deg) {
  int k = blockIdx.x * blockDim.x + threadIdx.x;
  if (k >= ET) return;
  int d = (k < E_PPI) ? dst_idx[k] : (k - E_PPI);
  atomicAdd(&deg[d], 1);
}

__global__ void scan_kernel(const int* __restrict__ deg, int* __restrict__ row_ptr) {
  __shared__ int buf[1024];
  __shared__ int carry_s;
  int tid = threadIdx.x;
  if (tid == 0) carry_s = 0;
  __syncthreads();
  const int n = NP + 1;
  for (int base = 0; base < n; base += 1024) {
    int idx = base + tid;
    int v = (idx < n) ? deg[idx] : 0;
    buf[tid] = v;
    __syncthreads();
    for (int off = 1; off < 1024; off <<= 1) {
      int t = (tid >= off) ? buf[tid - off] : 0;
      __syncthreads();
      buf[tid] += t;
      __syncthreads();
    }
    if (idx < n) row_ptr[idx] = carry_s + buf[tid] - v;  // exclusive scan
    __syncthreads();
    if (tid == 0) carry_s += buf[1023];
    __syncthreads();
  }
}

__global__ void cursor_init(const int* __restrict__ row_ptr, int* __restrict__ cursor) {
  int i = blockIdx.x * blockDim.x + threadIdx.x;
  if (i < NP) cursor[i] = row_ptr[i];
}

// fills src_perm: source node id per CSR slot (dst-sorted)
__global__ void fill_kernel(const int* __restrict__ src_idx, const int* __restrict__ dst_idx,
                            int* __restrict__ cursor, int* __restrict__ src_perm) {
  int k = blockIdx.x * blockDim.x + threadIdx.x;
  if (k >= ET) return;
  int s, d;
  if (k < E_PPI) { s = src_idx[k]; d = dst_idx[k]; }
  else           { s = d = k - E_PPI; }
  int pos = atomicAdd(&cursor[d], 1);
  src_perm[pos] = s;
}

// ---------------- B-weight pack into MFMA fragment order (bf16) ----------------
// GEMM reads: Bp[((tile*KB + kb)*64 + lane)*8 + j] = B[kb*32 + (lane>>4)*8 + j][tile*16 + (lane&15)]

template<int K, int N>
__global__ void pack_B(const float* __restrict__ B, short* __restrict__ Bp) {
  constexpr int KB = K / 32, TILES = N / 16;
  int idx = blockIdx.x * blockDim.x + threadIdx.x;
  if (idx >= TILES * KB * 64) return;
  int lane = idx & 63;
  int rest = idx >> 6;
  int kb = rest % KB;
  int tile = rest / KB;
  int n = tile * 16 + (lane & 15);
  int k0 = kb * 32 + (lane >> 4) * 8;
  short* o = Bp + (size_t)idx * 8;
#pragma unroll
  for (int j = 0; j < 8; ++j) o[j] = f2bs(B[(size_t)(k0 + j) * N + n]);
}

// ---------------- MFMA GEMM: Cb[M,N](bf16) = A[M,K] @ B[K,N] ----------------
// 16 rows per block, 4 waves each owning N/4 columns. No LDS needed (K<=256).
// A fragment: lane holds A[m0 + (lane&15)][kb*32 + (lane>>4)*8 + j], contiguous 16B.

template<int K, int N, bool AF32>
__launch_bounds__(256)
__global__ void gemm_mfma(const void* __restrict__ Av, const short* __restrict__ Bp,
                          short* __restrict__ Cb) {
  constexpr int KB = K / 32;
  constexpr int TPW = N / 64;   // 16-col tiles per wave
  int lane = threadIdx.x & 63, wave = threadIdx.x >> 6;
  int ln16 = lane & 15, quad = lane >> 4;
  int m0 = blockIdx.x * 16;
  float4v acc[TPW];
#pragma unroll
  for (int t = 0; t < TPW; ++t) acc[t] = (float4v)0.f;
#pragma unroll
  for (int kb = 0; kb < KB; ++kb) {
    int ka = kb * 32 + quad * 8;
    short8v afrag;
    if constexpr (AF32) {
      const float* ap = (const float*)Av + (size_t)(m0 + ln16) * K + ka;
      float4v a0 = *(const float4v*)ap;
      float4v a1 = *(const float4v*)(ap + 4);
#pragma unroll
      for (int j = 0; j < 4; ++j) { afrag[j] = f2bs(a0[j]); afrag[4 + j] = f2bs(a1[j]); }
    } else {
      afrag = *(const short8v*)((const short*)Av + (size_t)(m0 + ln16) * K + ka);
    }
#pragma unroll
    for (int t = 0; t < TPW; ++t) {
      int tile = wave * TPW + t;
      short8v bfrag = *(const short8v*)(Bp + ((size_t)(tile * KB + kb) * 64 + lane) * 8);
      acc[t] = __builtin_amdgcn_mfma_f32_16x16x32_bf16(afrag, bfrag, acc[t], 0, 0, 0);
    }
  }
  // C/D layout: col = lane&15, row = quad*4 + reg
#pragma unroll
  for (int t = 0; t < TPW; ++t) {
    int cc = (wave * TPW + t) * 16 + ln16;
#pragma unroll
    for (int r = 0; r < 4; ++r) {
      int rr = m0 + quad * 4 + r;
      Cb[(size_t)rr * N + cc] = f2bs(acc[t][r]);
    }
  }
}

// ---------------- attention scalars from bf16 h ----------------

template<int C>
__global__ void row_dots_bf(const short* __restrict__ h, const float* __restrict__ a_s,
                            const float* __restrict__ a_d, float* __restrict__ sb,
                            float* __restrict__ db) {
  int gid = blockIdx.x * blockDim.x + threadIdx.x;
  int node = gid >> 6, lane = gid & 63;
  if (node >= NP) return;
  constexpr int V = C / 64;
  float su = 0.f, dv = 0.f;
  const short* row = h + (size_t)node * C + lane * V;
  if constexpr (V == 4) {
    short4v x = *(const short4v*)row;
#pragma unroll
    for (int v = 0; v < 4; ++v) {
      float xv = bs2f(x[v]);
      su = fmaf(xv, a_s[lane * 4 + v], su);
      dv = fmaf(xv, a_d[lane * 4 + v], dv);
    }
  } else {
    short2v x = *(const short2v*)row;
#pragma unroll
    for (int v = 0; v < 2; ++v) {
      float xv = bs2f(x[v]);
      su = fmaf(xv, a_s[lane * 2 + v], su);
      dv = fmaf(xv, a_d[lane * 2 + v], dv);
    }
  }
  for (int off = 32; off > 0; off >>= 1) {
    su += __shfl_xor(su, off);
    dv += __shfl_xor(dv, off);
  }
  if (lane == 0) { sb[node] = su; db[node] = dv; }
}

// ---------------- fused logits + segment softmax -> normalized weights ----------------

__global__ void mden_fused(const float* __restrict__ sb, const float* __restrict__ db,
                           const int* __restrict__ src_perm, const int* __restrict__ row_ptr,
                           float* __restrict__ e_perm, float* __restrict__ w_perm) {
  int i = blockIdx.x * blockDim.x + threadIdx.x;
  if (i >= NP) return;
  int s = row_ptr[i], e = row_ptr[i + 1];
  float di = db[i];
  float m = -1e30f;
  for (int j = s; j < e; ++j) {
    float x = sb[src_perm[j]] + di;
    x = (x > 0.f) ? x : 0.2f * x;   // leaky_relu 0.2
    e_perm[j] = x;
    m = fmaxf(m, x);
  }
  float sum = 0.f;
  for (int j = s; j < e; ++j) {
    float t = __expf(e_perm[j] - m);
    w_perm[j] = t;
    sum += t;
  }
  float inv = 1.0f / sum;  // degree >= 1 (self loop)
  for (int j = s; j < e; ++j) w_perm[j] *= inv;
}

// ---------------- aggregation, layer a: C=256, bf16 in, relu+bias, bf16 out ----------------

__launch_bounds__(256)
__global__ void agg_a(const short* __restrict__ h, const int* __restrict__ src_perm,
                      const float* __restrict__ w_perm, const int* __restrict__ row_ptr,
                      const float* __restrict__ bias, short* __restrict__ outb) {
  int gid = blockIdx.x * blockDim.x + threadIdx.x;
  int dst = gid >> 6, lane = gid & 63;
  if (dst >= NP) return;
  float acc[4] = {0.f, 0.f, 0.f, 0.f};
  int s = row_ptr[dst], e = row_ptr[dst + 1];
  for (int j = s; j < e; ++j) {
    int src = src_perm[j];
    float w = w_perm[j];
    short4v x = *(const short4v*)(h + (size_t)src * 256 + lane * 4);
#pragma unroll
    for (int v = 0; v < 4; ++v) acc[v] = fmaf(w, bs2f(x[v]), acc[v]);
  }
  short4v o;
#pragma unroll
  for (int v = 0; v < 4; ++v) o[v] = f2bs(fmaxf(acc[v] + bias[lane * 4 + v], 0.f));
  *(short4v*)(outb + (size_t)dst * 256 + lane * 4) = o;
}

// ---------------- aggregation, layer b: C=128, bf16 in, bias, f32 out ----------------
// two edges per wave iteration (32 lanes each), cross-half reduce at the end

__launch_bounds__(256)
__global__ void agg_b(const short* __restrict__ h, const int* __restrict__ src_perm,
                      const float* __restrict__ w_perm, const int* __restrict__ row_ptr,
                      const float* __restrict__ bias, float* __restrict__ out) {
  int gid = blockIdx.x * blockDim.x + threadIdx.x;
  int dst = gid >> 6, lane = gid & 63;
  if (dst >= NP) return;
  int half = lane >> 5, l32 = lane & 31;
  float acc[4] = {0.f, 0.f, 0.f, 0.f};
  int s = row_ptr[dst], e = row_ptr[dst + 1], nj = e - s;
  for (int jj = 0; jj < nj; jj += 2) {
    int o = jj + half;
    float w = 0.f; int src = 0;
    if (o < nj) { w = w_perm[s + o]; src = src_perm[s + o]; }
    short4v x = *(const short4v*)(h + (size_t)src * 128 + l32 * 4);
#pragma unroll
    for (int v = 0; v < 4; ++v) acc[v] = fmaf(w, bs2f(x[v]), acc[v]);
  }
#pragma unroll
  for (int v = 0; v < 4; ++v) acc[v] += __shfl_xor(acc[v], 32);
  if (half == 0) {
    float4v o;
#pragma unroll
    for (int v = 0; v < 4; ++v) o[v] = acc[v] + bias[l32 * 4 + v];
    *(float4v*)(out + (size_t)dst * 128 + l32 * 4) = o;
  }
}

// ---------------- head ----------------

__global__ void uv_kernel(const float* __restrict__ hp2, const float* __restrict__ Wout,
                          float* __restrict__ u, float* __restrict__ v) {
  int gid = blockIdx.x * blockDim.x + threadIdx.x;
  int node = gid >> 6, lane = gid & 63;
  if (node >= NP) return;
  const float* row = hp2 + (size_t)node * 128;
  float x0 = row[lane], x1 = row[lane + 64];
  float su = fmaf(x0, Wout[lane], x1 * Wout[lane + 64]);
  float sv = fmaf(x0, Wout[128 + lane], x1 * Wout[192 + lane]);
  for (int off = 32; off > 0; off >>= 1) {
    su += __shfl_xor(su, off);
    sv += __shfl_xor(sv, off);
  }
  if (lane == 0) { u[node] = su; v[node] = sv; }
}

__global__ void out_kernel(const int* __restrict__ mask, const float* __restrict__ u,
                           const float* __restrict__ v, const float* __restrict__ bout,
                           float* __restrict__ out) {
  int p = blockIdx.x * blockDim.x + threadIdx.x;
  if (p >= NPAIR) return;
  int a = mask[2 * p], b = mask[2 * p + 1];
  float logit = u[a] + v[b] + bout[0];
  out[p] = 1.0f / (1.0f + __expf(-logit));
}

// ---------------- launch ----------------

extern "C" void kernel_launch(void* const* d_in, const int* in_sizes, int n_in,
                              void* d_out, int out_size, void* d_ws, size_t ws_size,
                              hipStream_t stream) {
  const float* xp   = (const float*)d_in[0];
  const int*   ei   = (const int*)d_in[5];          // ei_ppi (2, E_PPI)
  const int*   mask = (const int*)d_in[6];
  const float* Wa2  = (const float*)d_in[7]  + 2 * F * H;   // Wa[2]  [128,256]
  const float* asa  = (const float*)d_in[8]  + 2 * H;
  const float* ada  = (const float*)d_in[9]  + 2 * H;
  const float* ba   = (const float*)d_in[10] + 2 * H;
  const float* Wb2  = (const float*)d_in[11] + 2 * H * F;   // Wb[2]  [256,128]
  const float* asb  = (const float*)d_in[12] + 2 * F;
  const float* adb  = (const float*)d_in[13] + 2 * F;
  const float* bb   = (const float*)d_in[14] + 2 * F;
  const float* Wout = (const float*)d_in[21];
  const float* bout = (const float*)d_in[22];
  float* out = (float*)d_out;

  // workspace layout (256B-aligned slices)
  char* ws = (char*)d_ws;
  size_t off = 0;
  auto alloc = [&](size_t bytes) {
    void* p = ws + off;
    off = (off + bytes + 255) & ~(size_t)255;
    return p;
  };
  short* h1b     = (short*)alloc((size_t)NP * H * 2);      // bf16 [50000,256]
  short* hpb     = (short*)alloc((size_t)NP * H * 2);      // bf16 relu'd layer-a out
  short* h2b     = (short*)alloc((size_t)NP * F * 2);      // bf16 [50000,128]
  float* hp2     = (float*)alloc((size_t)NP * F * 4);      // f32 layer-b out
  float* e_perm  = (float*)alloc((size_t)ET * 4);
  float* w_perm  = (float*)alloc((size_t)ET * 4);
  int*   src_perm= (int*)alloc((size_t)ET * 4);
  int*   row_ptr = (int*)alloc((size_t)(NP + 1) * 4);
  int*   cursor  = (int*)alloc((size_t)NP * 4);
  int*   deg     = (int*)alloc((size_t)(NP + 1) * 4);
  float* sb      = (float*)alloc((size_t)NP * 4);
  float* db      = (float*)alloc((size_t)NP * 4);
  float* u       = (float*)alloc((size_t)NP * 4);
  float* v       = (float*)alloc((size_t)NP * 4);
  short* BaP     = (short*)alloc((size_t)F * H * 2);       // packed Wa2
  short* BbP     = (short*)alloc((size_t)H * F * 2);       // packed Wb2

  const int* src_idx = ei;
  const int* dst_idx = ei + E_PPI;

  // CSR over ppi edges + self loops (shared by both layers)
  hipMemsetAsync(deg, 0, (size_t)(NP + 1) * 4, stream);
  deg_kernel<<<(ET + 255) / 256, 256, 0, stream>>>(dst_idx, deg);
  scan_kernel<<<1, 1024, 0, stream>>>(deg, row_ptr);
  cursor_init<<<(NP + 255) / 256, 256, 0, stream>>>(row_ptr, cursor);
  fill_kernel<<<(ET + 255) / 256, 256, 0, stream>>>(src_idx, dst_idx, cursor, src_perm);

  // pack weights into MFMA fragment order
  pack_B<F, H><<<(16 * 4 * 64 + 255) / 256, 256, 0, stream>>>(Wa2, BaP);
  pack_B<H, F><<<(8 * 8 * 64 + 255) / 256, 256, 0, stream>>>(Wb2, BbP);

  int node_wave_blocks = (NP + 3) / 4;   // wave per node, 4 waves/block

  // ---- layer a: h1 = xp @ Wa2 (bf16 out), GAT over ppi, relu ----
  gemm_mfma<F, H, true><<<NP / 16, 256, 0, stream>>>(xp, BaP, h1b);
  row_dots_bf<H><<<node_wave_blocks, 256, 0, stream>>>(h1b, asa, ada, sb, db);
  mden_fused<<<(NP + 255) / 256, 256, 0, stream>>>(sb, db, src_perm, row_ptr, e_perm, w_perm);
  agg_a<<<node_wave_blocks, 256, 0, stream>>>(h1b, src_perm, w_perm, row_ptr, ba, hpb);

  // ---- layer b: h2 = hp @ Wb2 (bf16 out), GAT over ppi ----
  gemm_mfma<H, F, false><<<NP / 16, 256, 0, stream>>>(hpb, BbP, h2b);
  row_dots_bf<F><<<node_wave_blocks, 256, 0, stream>>>(h2b, asb, adb, sb, db);
  mden_fused<<<(NP + 255) / 256, 256, 0, stream>>>(sb, db, src_perm, row_ptr, e_perm, w_perm);
  agg_b<<<node_wave_blocks, 256, 0, stream>>>(h2b, src_perm, w_perm, row_ptr, bb, hp2);

  // ---- link-prediction head ----
  uv_kernel<<<node_wave_blocks, 256, 0, stream>>>(hp2, Wout, u, v);
  out_kernel<<<(NPAIR + 255) / 256, 256, 0, stream>>>(mask, u, v, bout, out);
}

// Round 3
// 425.287 us; speedup vs baseline: 1.8178x; 1.3566x over previous
//
#include <hip/hip_runtime.h>
#include <hip/hip_bf16.h>
#include <math.h>

#define NP 50000
#define F 128
#define H 256
#define E_PPI 800000
#define ET (E_PPI + NP)   // edges + self loops
#define NPAIR 200000
#define NSCAN (NP + 1)
#define NB_SCAN ((NSCAN + 1023) / 1024)   // 49

typedef __attribute__((ext_vector_type(8))) short short8v;
typedef __attribute__((ext_vector_type(4))) short short4v;
typedef __attribute__((ext_vector_type(4))) float float4v;

__device__ __forceinline__ short f2bs(float f) {  // f32 -> bf16 bits, RNE
  unsigned u = __builtin_bit_cast(unsigned, f);
  unsigned r = (u + 0x7FFFu + ((u >> 16) & 1u)) >> 16;
  return (short)r;
}
__device__ __forceinline__ float bs2f(short s) {
  unsigned u = ((unsigned)(unsigned short)s) << 16;
  return __builtin_bit_cast(float, u);
}

// ---------------- CSR build ----------------

__global__ void deg_kernel(const int* __restrict__ dst_idx, int* __restrict__ deg) {
  int k = blockIdx.x * blockDim.x + threadIdx.x;
  if (k >= ET) return;
  int d = (k < E_PPI) ? dst_idx[k] : (k - E_PPI);
  atomicAdd(&deg[d], 1);
}

// phase 1: per-block exclusive scan of 1024-elem tiles + block sums
__global__ void scan_partial(const int* __restrict__ deg, int* __restrict__ row_ptr,
                             int* __restrict__ bsum) {
  __shared__ int buf[1024];
  int tid = threadIdx.x;
  int idx = blockIdx.x * 1024 + tid;
  int v = (idx < NSCAN) ? deg[idx] : 0;   // deg[NP] stays 0
  buf[tid] = v;
  __syncthreads();
  for (int off = 1; off < 1024; off <<= 1) {
    int t = (tid >= off) ? buf[tid - off] : 0;
    __syncthreads();
    buf[tid] += t;
    __syncthreads();
  }
  if (idx < NSCAN) row_ptr[idx] = buf[tid] - v;     // exclusive within block
  if (tid == 1023) bsum[blockIdx.x] = buf[1023];
}

// phase 2: exclusive scan of 49 block sums in a single wave
__global__ void scan_sums(int* __restrict__ bsum) {
  int lane = threadIdx.x;
  int v = (lane < NB_SCAN) ? bsum[lane] : 0;
  for (int off = 1; off < 64; off <<= 1) {
    int t = __shfl_up(v, off);
    if (lane >= off) v += t;
  }
  int ex = __shfl_up(v, 1);
  if (lane == 0) ex = 0;
  if (lane < NB_SCAN) bsum[lane] = ex;
}

// phase 3: add block offsets; also initialize fill cursor
__global__ void scan_add(int* __restrict__ row_ptr, int* __restrict__ cursor,
                         const int* __restrict__ bsum) {
  int idx = blockIdx.x * blockDim.x + threadIdx.x;
  if (idx >= NSCAN) return;
  int v = row_ptr[idx] + bsum[idx >> 10];
  row_ptr[idx] = v;
  if (idx < NP) cursor[idx] = v;
}

// fills src_perm: source node id per CSR slot (dst-sorted)
__global__ void fill_kernel(const int* __restrict__ src_idx, const int* __restrict__ dst_idx,
                            int* __restrict__ cursor, int* __restrict__ src_perm) {
  int k = blockIdx.x * blockDim.x + threadIdx.x;
  if (k >= ET) return;
  int s, d;
  if (k < E_PPI) { s = src_idx[k]; d = dst_idx[k]; }
  else           { s = d = k - E_PPI; }
  int pos = atomicAdd(&cursor[d], 1);
  src_perm[pos] = s;
}

// ---------------- B-weight pack into MFMA fragment order (bf16) ----------------

template<int K, int N>
__global__ void pack_B(const float* __restrict__ B, short* __restrict__ Bp) {
  constexpr int KB = K / 32, TILES = N / 16;
  int idx = blockIdx.x * blockDim.x + threadIdx.x;
  if (idx >= TILES * KB * 64) return;
  int lane = idx & 63;
  int rest = idx >> 6;
  int kb = rest % KB;
  int tile = rest / KB;
  int n = tile * 16 + (lane & 15);
  int k0 = kb * 32 + (lane >> 4) * 8;
  short* o = Bp + (size_t)idx * 8;
#pragma unroll
  for (int j = 0; j < 8; ++j) o[j] = f2bs(B[(size_t)(k0 + j) * N + n]);
}

// ---------------- MFMA GEMM + fused attention dots ----------------
// 16 rows per block, 4 waves each owning N/4 columns (covers all N cols per block).
// Epilogue: sb[i] = h_i . a_s, db[i] = h_i . a_d from f32 accumulators.

template<int K, int N, bool AF32>
__launch_bounds__(256)
__global__ void gemm_mfma(const void* __restrict__ Av, const short* __restrict__ Bp,
                          short* __restrict__ Cb, const float* __restrict__ a_s,
                          const float* __restrict__ a_d, float* __restrict__ sb,
                          float* __restrict__ db) {
  constexpr int KB = K / 32;
  constexpr int TPW = N / 64;   // 16-col tiles per wave
  __shared__ float sred[4][16];
  __shared__ float dred[4][16];
  int lane = threadIdx.x & 63, wave = threadIdx.x >> 6;
  int ln16 = lane & 15, quad = lane >> 4;
  int m0 = blockIdx.x * 16;
  float4v acc[TPW];
#pragma unroll
  for (int t = 0; t < TPW; ++t) acc[t] = (float4v)0.f;
#pragma unroll
  for (int kb = 0; kb < KB; ++kb) {
    int ka = kb * 32 + quad * 8;
    short8v afrag;
    if constexpr (AF32) {
      const float* ap = (const float*)Av + (size_t)(m0 + ln16) * K + ka;
      float4v a0 = *(const float4v*)ap;
      float4v a1 = *(const float4v*)(ap + 4);
#pragma unroll
      for (int j = 0; j < 4; ++j) { afrag[j] = f2bs(a0[j]); afrag[4 + j] = f2bs(a1[j]); }
    } else {
      afrag = *(const short8v*)((const short*)Av + (size_t)(m0 + ln16) * K + ka);
    }
#pragma unroll
    for (int t = 0; t < TPW; ++t) {
      int tile = wave * TPW + t;
      short8v bfrag = *(const short8v*)(Bp + ((size_t)(tile * KB + kb) * 64 + lane) * 8);
      acc[t] = __builtin_amdgcn_mfma_f32_16x16x32_bf16(afrag, bfrag, acc[t], 0, 0, 0);
    }
  }
  // store h (bf16); C/D layout: col = lane&15, row = quad*4 + reg
#pragma unroll
  for (int t = 0; t < TPW; ++t) {
    int cc = (wave * TPW + t) * 16 + ln16;
#pragma unroll
    for (int r = 0; r < 4; ++r) {
      int rr = m0 + quad * 4 + r;
      Cb[(size_t)rr * N + cc] = f2bs(acc[t][r]);
    }
  }
  // fused dots: partial over this wave's 16*TPW columns for rows quad*4+r
  float su[4] = {0.f, 0.f, 0.f, 0.f}, dv[4] = {0.f, 0.f, 0.f, 0.f};
#pragma unroll
  for (int t = 0; t < TPW; ++t) {
    int cc = (wave * TPW + t) * 16 + ln16;
    float as = a_s[cc], ad = a_d[cc];
#pragma unroll
    for (int r = 0; r < 4; ++r) {
      su[r] = fmaf(acc[t][r], as, su[r]);
      dv[r] = fmaf(acc[t][r], ad, dv[r]);
    }
  }
#pragma unroll
  for (int r = 0; r < 4; ++r) {
    for (int off = 1; off < 16; off <<= 1) {
      su[r] += __shfl_xor(su[r], off);
      dv[r] += __shfl_xor(dv[r], off);
    }
  }
  if (ln16 == 0) {
#pragma unroll
    for (int r = 0; r < 4; ++r) {
      sred[wave][quad * 4 + r] = su[r];
      dred[wave][quad * 4 + r] = dv[r];
    }
  }
  __syncthreads();
  if (threadIdx.x < 16) {
    int row = threadIdx.x;
    float s_t = sred[0][row] + sred[1][row] + sred[2][row] + sred[3][row];
    float d_t = dred[0][row] + dred[1][row] + dred[2][row] + dred[3][row];
    sb[m0 + row] = s_t;
    db[m0 + row] = d_t;
  }
}

// ---------------- fused logits + segment softmax (unnormalized w + inv) ----------------

__global__ void mden_fused(const float* __restrict__ sb, const float* __restrict__ db,
                           const int* __restrict__ src_perm, const int* __restrict__ row_ptr,
                           float* __restrict__ w_perm, float* __restrict__ invd) {
  int i = blockIdx.x * blockDim.x + threadIdx.x;
  if (i >= NP) return;
  int s = row_ptr[i], e = row_ptr[i + 1];
  float di = db[i];
  float m = -1e30f;
  for (int j = s; j < e; ++j) {
    float x = sb[src_perm[j]] + di;
    x = (x > 0.f) ? x : 0.2f * x;   // leaky_relu 0.2
    w_perm[j] = x;
    m = fmaxf(m, x);
  }
  float sum = 0.f;
  for (int j = s; j < e; ++j) {
    float t = __expf(w_perm[j] - m);
    w_perm[j] = t;
    sum += t;
  }
  invd[i] = 1.0f / sum;  // degree >= 1 (self loop)
}

// ---------------- aggregation, layer a: C=256, 2 edges/wave, 16B gathers ----------------

__launch_bounds__(256)
__global__ void agg_a(const short* __restrict__ h, const int* __restrict__ src_perm,
                      const float* __restrict__ w_perm, const int* __restrict__ row_ptr,
                      const float* __restrict__ invd, const float* __restrict__ bias,
                      short* __restrict__ outb) {
  int gid = blockIdx.x * blockDim.x + threadIdx.x;
  int dst = gid >> 6, lane = gid & 63;
  if (dst >= NP) return;
  int half = lane >> 5, l32 = lane & 31;
  float acc[8] = {0.f, 0.f, 0.f, 0.f, 0.f, 0.f, 0.f, 0.f};
  int s = row_ptr[dst], e = row_ptr[dst + 1];
  for (int j = s + half; j < e; j += 2) {
    float w = w_perm[j];
    int src = src_perm[j];
    short8v x = *(const short8v*)(h + (size_t)src * 256 + l32 * 8);
#pragma unroll
    for (int v = 0; v < 8; ++v) acc[v] = fmaf(w, bs2f(x[v]), acc[v]);
  }
#pragma unroll
  for (int v = 0; v < 8; ++v) acc[v] += __shfl_xor(acc[v], 32);
  if (half == 0) {
    float inv = invd[dst];
    short8v o;
#pragma unroll
    for (int v = 0; v < 8; ++v)
      o[v] = f2bs(fmaxf(fmaf(acc[v], inv, bias[l32 * 8 + v]), 0.f));
    *(short8v*)(outb + (size_t)dst * 256 + l32 * 8) = o;
  }
}

// ---------------- aggregation, layer b: C=128, 4 edges/wave, 16B gathers, f32 out ----------------

__launch_bounds__(256)
__global__ void agg_b(const short* __restrict__ h, const int* __restrict__ src_perm,
                      const float* __restrict__ w_perm, const int* __restrict__ row_ptr,
                      const float* __restrict__ invd, const float* __restrict__ bias,
                      float* __restrict__ out) {
  int gid = blockIdx.x * blockDim.x + threadIdx.x;
  int dst = gid >> 6, lane = gid & 63;
  if (dst >= NP) return;
  int grp = lane >> 4, l16 = lane & 15;
  float acc[8] = {0.f, 0.f, 0.f, 0.f, 0.f, 0.f, 0.f, 0.f};
  int s = row_ptr[dst], e = row_ptr[dst + 1];
  for (int j = s + grp; j < e; j += 4) {
    float w = w_perm[j];
    int src = src_perm[j];
    short8v x = *(const short8v*)(h + (size_t)src * 128 + l16 * 8);
#pragma unroll
    for (int v = 0; v < 8; ++v) acc[v] = fmaf(w, bs2f(x[v]), acc[v]);
  }
#pragma unroll
  for (int v = 0; v < 8; ++v) {
    acc[v] += __shfl_xor(acc[v], 16);
    acc[v] += __shfl_xor(acc[v], 32);
  }
  if (lane < 16) {
    float inv = invd[dst];
    float4v o0, o1;
#pragma unroll
    for (int v = 0; v < 4; ++v) {
      o0[v] = fmaf(acc[v], inv, bias[l16 * 8 + v]);
      o1[v] = fmaf(acc[4 + v], inv, bias[l16 * 8 + 4 + v]);
    }
    float* op = out + (size_t)dst * 128 + l16 * 8;
    *(float4v*)op = o0;
    *(float4v*)(op + 4) = o1;
  }
}

// ---------------- head ----------------

__global__ void uv_kernel(const float* __restrict__ hp2, const float* __restrict__ Wout,
                          float* __restrict__ u, float* __restrict__ v) {
  int gid = blockIdx.x * blockDim.x + threadIdx.x;
  int node = gid >> 6, lane = gid & 63;
  if (node >= NP) return;
  const float* row = hp2 + (size_t)node * 128;
  float x0 = row[lane], x1 = row[lane + 64];
  float su = fmaf(x0, Wout[lane], x1 * Wout[lane + 64]);
  float sv = fmaf(x0, Wout[128 + lane], x1 * Wout[192 + lane]);
  for (int off = 32; off > 0; off >>= 1) {
    su += __shfl_xor(su, off);
    sv += __shfl_xor(sv, off);
  }
  if (lane == 0) { u[node] = su; v[node] = sv; }
}

__global__ void out_kernel(const int* __restrict__ mask, const float* __restrict__ u,
                           const float* __restrict__ v, const float* __restrict__ bout,
                           float* __restrict__ out) {
  int p = blockIdx.x * blockDim.x + threadIdx.x;
  if (p >= NPAIR) return;
  int a = mask[2 * p], b = mask[2 * p + 1];
  float logit = u[a] + v[b] + bout[0];
  out[p] = 1.0f / (1.0f + __expf(-logit));
}

// ---------------- launch ----------------

extern "C" void kernel_launch(void* const* d_in, const int* in_sizes, int n_in,
                              void* d_out, int out_size, void* d_ws, size_t ws_size,
                              hipStream_t stream) {
  const float* xp   = (const float*)d_in[0];
  const int*   ei   = (const int*)d_in[5];          // ei_ppi (2, E_PPI)
  const int*   mask = (const int*)d_in[6];
  const float* Wa2  = (const float*)d_in[7]  + 2 * F * H;   // Wa[2]  [128,256]
  const float* asa  = (const float*)d_in[8]  + 2 * H;
  const float* ada  = (const float*)d_in[9]  + 2 * H;
  const float* ba   = (const float*)d_in[10] + 2 * H;
  const float* Wb2  = (const float*)d_in[11] + 2 * H * F;   // Wb[2]  [256,128]
  const float* asb  = (const float*)d_in[12] + 2 * F;
  const float* adb  = (const float*)d_in[13] + 2 * F;
  const float* bb   = (const float*)d_in[14] + 2 * F;
  const float* Wout = (const float*)d_in[21];
  const float* bout = (const float*)d_in[22];
  float* out = (float*)d_out;

  // workspace layout (256B-aligned slices)
  char* ws = (char*)d_ws;
  size_t off = 0;
  auto alloc = [&](size_t bytes) {
    void* p = ws + off;
    off = (off + bytes + 255) & ~(size_t)255;
    return p;
  };
  short* h1b     = (short*)alloc((size_t)NP * H * 2);      // bf16 [50000,256]
  short* hpb     = (short*)alloc((size_t)NP * H * 2);      // bf16 relu'd layer-a out
  short* h2b     = (short*)alloc((size_t)NP * F * 2);      // bf16 [50000,128]
  float* hp2     = (float*)alloc((size_t)NP * F * 4);      // f32 layer-b out
  float* w_perm  = (float*)alloc((size_t)ET * 4);
  int*   src_perm= (int*)alloc((size_t)ET * 4);
  int*   row_ptr = (int*)alloc((size_t)NSCAN * 4);
  int*   cursor  = (int*)alloc((size_t)NP * 4);
  int*   deg     = (int*)alloc((size_t)NSCAN * 4);
  int*   bsum    = (int*)alloc((size_t)NB_SCAN * 4);
  float* sb      = (float*)alloc((size_t)NP * 4);
  float* db      = (float*)alloc((size_t)NP * 4);
  float* invd    = (float*)alloc((size_t)NP * 4);
  float* u       = (float*)alloc((size_t)NP * 4);
  float* v       = (float*)alloc((size_t)NP * 4);
  short* BaP     = (short*)alloc((size_t)F * H * 2);       // packed Wa2
  short* BbP     = (short*)alloc((size_t)H * F * 2);       // packed Wb2

  const int* src_idx = ei;
  const int* dst_idx = ei + E_PPI;

  // CSR over ppi edges + self loops (shared by both layers)
  hipMemsetAsync(deg, 0, (size_t)NSCAN * 4, stream);
  deg_kernel<<<(ET + 255) / 256, 256, 0, stream>>>(dst_idx, deg);
  scan_partial<<<NB_SCAN, 1024, 0, stream>>>(deg, row_ptr, bsum);
  scan_sums<<<1, 64, 0, stream>>>(bsum);
  scan_add<<<(NSCAN + 255) / 256, 256, 0, stream>>>(row_ptr, cursor, bsum);
  fill_kernel<<<(ET + 255) / 256, 256, 0, stream>>>(src_idx, dst_idx, cursor, src_perm);

  // pack weights into MFMA fragment order
  pack_B<F, H><<<(16 * 4 * 64 + 255) / 256, 256, 0, stream>>>(Wa2, BaP);
  pack_B<H, F><<<(8 * 8 * 64 + 255) / 256, 256, 0, stream>>>(Wb2, BbP);

  int node_wave_blocks = (NP + 3) / 4;   // wave per node, 4 waves/block

  // ---- layer a: h1 = xp @ Wa2 (bf16 out, fused dots), softmax, aggregate+relu ----
  gemm_mfma<F, H, true><<<NP / 16, 256, 0, stream>>>(xp, BaP, h1b, asa, ada, sb, db);
  mden_fused<<<(NP + 255) / 256, 256, 0, stream>>>(sb, db, src_perm, row_ptr, w_perm, invd);
  agg_a<<<node_wave_blocks, 256, 0, stream>>>(h1b, src_perm, w_perm, row_ptr, invd, ba, hpb);

  // ---- layer b: h2 = hp @ Wb2 (bf16 out, fused dots), softmax, aggregate ----
  gemm_mfma<H, F, false><<<NP / 16, 256, 0, stream>>>(hpb, BbP, h2b, asb, adb, sb, db);
  mden_fused<<<(NP + 255) / 256, 256, 0, stream>>>(sb, db, src_perm, row_ptr, w_perm, invd);
  agg_b<<<node_wave_blocks, 256, 0, stream>>>(h2b, src_perm, w_perm, row_ptr, invd, bb, hp2);

  // ---- link-prediction head ----
  uv_kernel<<<node_wave_blocks, 256, 0, stream>>>(hp2, Wout, u, v);
  out_kernel<<<(NPAIR + 255) / 256, 256, 0, stream>>>(mask, u, v, bout, out);
}

// Round 6
// 420.573 us; speedup vs baseline: 1.8382x; 1.0112x over previous
//
#include <hip/hip_runtime.h>
#include <hip/hip_bf16.h>
#include <math.h>

#define NP 50000
#define F 128
#define H 256
#define E_PPI 800000
#define ET (E_PPI + NP)   // edges + self loops
#define NPAIR 200000
#define NSCAN (NP + 1)
#define NB_SCAN ((NSCAN + 1023) / 1024)   // 49

typedef __attribute__((ext_vector_type(8))) short short8v;
typedef __attribute__((ext_vector_type(4))) float float4v;

__device__ __forceinline__ short f2bs(float f) {  // f32 -> bf16 bits, RNE
  unsigned u = __builtin_bit_cast(unsigned, f);
  unsigned r = (u + 0x7FFFu + ((u >> 16) & 1u)) >> 16;
  return (short)r;
}
__device__ __forceinline__ float bs2f(short s) {
  unsigned u = ((unsigned)(unsigned short)s) << 16;
  return __builtin_bit_cast(float, u);
}
__device__ __forceinline__ float lrelu(float t) { return (t > 0.f) ? t : 0.2f * t; }

// ---------------- CSR build ----------------

__global__ void deg_kernel(const int* __restrict__ dst_idx, int* __restrict__ deg) {
  int k = blockIdx.x * blockDim.x + threadIdx.x;
  if (k >= ET) return;
  int d = (k < E_PPI) ? dst_idx[k] : (k - E_PPI);
  atomicAdd(&deg[d], 1);
}

__global__ void scan_partial(const int* __restrict__ deg, int* __restrict__ row_ptr,
                             int* __restrict__ bsum) {
  __shared__ int buf[1024];
  int tid = threadIdx.x;
  int idx = blockIdx.x * 1024 + tid;
  int v = (idx < NSCAN) ? deg[idx] : 0;   // deg[NP] stays 0
  buf[tid] = v;
  __syncthreads();
  for (int off = 1; off < 1024; off <<= 1) {
    int t = (tid >= off) ? buf[tid - off] : 0;
    __syncthreads();
    buf[tid] += t;
    __syncthreads();
  }
  if (idx < NSCAN) row_ptr[idx] = buf[tid] - v;     // exclusive within block
  if (tid == 1023) bsum[blockIdx.x] = buf[1023];
}

__global__ void scan_sums(int* __restrict__ bsum) {
  int lane = threadIdx.x;
  int v = (lane < NB_SCAN) ? bsum[lane] : 0;
  for (int off = 1; off < 64; off <<= 1) {
    int t = __shfl_up(v, off);
    if (lane >= off) v += t;
  }
  int ex = __shfl_up(v, 1);
  if (lane == 0) ex = 0;
  if (lane < NB_SCAN) bsum[lane] = ex;
}

__global__ void scan_add(int* __restrict__ row_ptr, int* __restrict__ cursor,
                         const int* __restrict__ bsum) {
  int idx = blockIdx.x * blockDim.x + threadIdx.x;
  if (idx >= NSCAN) return;
  int v = row_ptr[idx] + bsum[idx >> 10];
  row_ptr[idx] = v;
  if (idx < NP) cursor[idx] = v;
}

__global__ void fill_kernel(const int* __restrict__ src_idx, const int* __restrict__ dst_idx,
                            int* __restrict__ cursor, int* __restrict__ src_perm) {
  int k = blockIdx.x * blockDim.x + threadIdx.x;
  if (k >= ET) return;
  int s, d;
  if (k < E_PPI) { s = src_idx[k]; d = dst_idx[k]; }
  else           { s = d = k - E_PPI; }
  int pos = atomicAdd(&cursor[d], 1);
  src_perm[pos] = s;
}

// ---------------- B-weight pack into MFMA fragment order, hi+lo bf16 split ----------------

template<int K, int N>
__global__ void pack_B(const float* __restrict__ B, short* __restrict__ Bh,
                       short* __restrict__ Bl) {
  constexpr int KB = K / 32, TILES = N / 16;
  int idx = blockIdx.x * blockDim.x + threadIdx.x;
  if (idx >= TILES * KB * 64) return;
  int lane = idx & 63;
  int rest = idx >> 6;
  int kb = rest % KB;
  int tile = rest / KB;
  int n = tile * 16 + (lane & 15);
  int k0 = kb * 32 + (lane >> 4) * 8;
  size_t base = (size_t)idx * 8;
#pragma unroll
  for (int j = 0; j < 8; ++j) {
    float x = B[(size_t)(k0 + j) * N + n];
    short hi = f2bs(x);
    Bh[base + j] = hi;
    Bl[base + j] = f2bs(x - bs2f(hi));
  }
}

// ---------------- split-precision MFMA GEMM + fused attention dots ----------------
// A f32 -> (hi,lo) bf16 pair in-kernel; acc += Ah*Bh + Al*Bh + Ah*Bl.

template<int K, int N, bool OUTBF>
__launch_bounds__(256)
__global__ void gemm_mfma(const float* __restrict__ A, const short* __restrict__ Bh,
                          const short* __restrict__ Bl, void* __restrict__ Cout,
                          const float* __restrict__ a_s, const float* __restrict__ a_d,
                          float* __restrict__ sb, float* __restrict__ db) {
  constexpr int KB = K / 32;
  constexpr int TPW = N / 64;   // 16-col tiles per wave
  __shared__ float sred[4][16];
  __shared__ float dred[4][16];
  int lane = threadIdx.x & 63, wave = threadIdx.x >> 6;
  int ln16 = lane & 15, quad = lane >> 4;
  int m0 = blockIdx.x * 16;
  float4v acc[TPW];
#pragma unroll
  for (int t = 0; t < TPW; ++t) acc[t] = (float4v)0.f;
#pragma unroll
  for (int kb = 0; kb < KB; ++kb) {
    int ka = kb * 32 + quad * 8;
    const float* ap = A + (size_t)(m0 + ln16) * K + ka;
    float4v a0 = *(const float4v*)ap;
    float4v a1 = *(const float4v*)(ap + 4);
    short8v ah, al;
#pragma unroll
    for (int j = 0; j < 4; ++j) {
      short h0 = f2bs(a0[j]); ah[j] = h0;     al[j] = f2bs(a0[j] - bs2f(h0));
      short h1 = f2bs(a1[j]); ah[4 + j] = h1; al[4 + j] = f2bs(a1[j] - bs2f(h1));
    }
#pragma unroll
    for (int t = 0; t < TPW; ++t) {
      int tile = wave * TPW + t;
      size_t boff = ((size_t)(tile * KB + kb) * 64 + lane) * 8;
      short8v bh = *(const short8v*)(Bh + boff);
      short8v bl = *(const short8v*)(Bl + boff);
      acc[t] = __builtin_amdgcn_mfma_f32_16x16x32_bf16(ah, bh, acc[t], 0, 0, 0);
      acc[t] = __builtin_amdgcn_mfma_f32_16x16x32_bf16(al, bh, acc[t], 0, 0, 0);
      acc[t] = __builtin_amdgcn_mfma_f32_16x16x32_bf16(ah, bl, acc[t], 0, 0, 0);
    }
  }
  // store h; C/D layout: col = lane&15, row = quad*4 + reg
#pragma unroll
  for (int t = 0; t < TPW; ++t) {
    int cc = (wave * TPW + t) * 16 + ln16;
#pragma unroll
    for (int r = 0; r < 4; ++r) {
      int rr = m0 + quad * 4 + r;
      if constexpr (OUTBF) ((short*)Cout)[(size_t)rr * N + cc] = f2bs(acc[t][r]);
      else                 ((float*)Cout)[(size_t)rr * N + cc] = acc[t][r];
    }
  }
  // fused dots over this wave's columns (f32 accs)
  float su[4] = {0.f, 0.f, 0.f, 0.f}, dv[4] = {0.f, 0.f, 0.f, 0.f};
#pragma unroll
  for (int t = 0; t < TPW; ++t) {
    int cc = (wave * TPW + t) * 16 + ln16;
    float as = a_s[cc], ad = a_d[cc];
#pragma unroll
    for (int r = 0; r < 4; ++r) {
      su[r] = fmaf(acc[t][r], as, su[r]);
      dv[r] = fmaf(acc[t][r], ad, dv[r]);
    }
  }
#pragma unroll
  for (int r = 0; r < 4; ++r) {
    for (int off = 1; off < 16; off <<= 1) {
      su[r] += __shfl_xor(su[r], off);
      dv[r] += __shfl_xor(dv[r], off);
    }
  }
  if (ln16 == 0) {
#pragma unroll
    for (int r = 0; r < 4; ++r) {
      sred[wave][quad * 4 + r] = su[r];
      dred[wave][quad * 4 + r] = dv[r];
    }
  }
  __syncthreads();
  if (threadIdx.x < 16) {
    int row = threadIdx.x;
    sb[m0 + row] = sred[0][row] + sred[1][row] + sred[2][row] + sred[3][row];
    db[m0 + row] = dred[0][row] + dred[1][row] + dred[2][row] + dred[3][row];
  }
}

// ---------------- fused softmax + aggregation, layer a ----------------
// Phase 2 trip count is WAVE-UNIFORM (it0 loop) so every __shfl executes with
// all 64 lanes active — sourcing x0 from any lane is well-defined. (Round-4 bug:
// per-group trip counts made shfl read exec-masked-off lanes -> garbage weights.)

__launch_bounds__(256)
__global__ void agg_a(const short* __restrict__ h, const int* __restrict__ src_perm,
                      const int* __restrict__ row_ptr, const float* __restrict__ sb,
                      const float* __restrict__ db, const float* __restrict__ bias,
                      float* __restrict__ outf) {
  int gid = blockIdx.x * blockDim.x + threadIdx.x;
  int dst = gid >> 6, lane = gid & 63;
  if (dst >= NP) return;
  int g = lane >> 4, l16 = lane & 15;
  int s = row_ptr[dst], deg = row_ptr[dst + 1] - s;
  float di = db[dst];
  // phase 1: lane-parallel online softmax stats; x0 = chunk-0 logits (lane i -> edge i)
  float m = -1e30f, ssum = 0.f, x0 = -1e30f;
  for (int c0 = 0; c0 < deg; c0 += 64) {
    int idx = c0 + lane;
    float x = -1e30f;
    if (idx < deg) x = lrelu(sb[src_perm[s + idx]] + di);
    if (c0 == 0) x0 = x;
    float cm = x;
#pragma unroll
    for (int o = 32; o; o >>= 1) cm = fmaxf(cm, __shfl_xor(cm, o));
    float nm = fmaxf(m, cm);
    float ex = (idx < deg) ? __expf(x - nm) : 0.f;
#pragma unroll
    for (int o = 32; o; o >>= 1) ex += __shfl_xor(ex, o);
    ssum = ssum * __expf(m - nm) + ex;
    m = nm;
  }
  float inv = 1.0f / ssum;
  // phase 2: uniform trip count; group g handles edges it0+g and it0+g+4
  float acc[16];
#pragma unroll
  for (int v = 0; v < 16; ++v) acc[v] = 0.f;
  for (int it0 = 0; it0 < deg; it0 += 8) {
    int it = it0 + g;
    int i2 = it + 4;
    bool v1 = (it < deg), v2 = (i2 < deg);
    int src1 = v1 ? src_perm[s + it] : src_perm[s];
    int src2 = v2 ? src_perm[s + i2] : src_perm[s];
    const short* p1 = h + (size_t)src1 * 256 + l16 * 16;
    const short* p2 = h + (size_t)src2 * 256 + l16 * 16;
    short8v a0 = *(const short8v*)p1;
    short8v a1 = *(const short8v*)(p1 + 8);
    short8v b0 = *(const short8v*)p2;
    short8v b1 = *(const short8v*)(p2 + 8);
    float xl1 = __shfl(x0, it & 63);   // uniform: all 64 lanes active
    float xl2 = __shfl(x0, i2 & 63);
    if (deg > 64) {                    // wave-uniform branch, no shfl inside
      if (it >= 64 && v1) xl1 = lrelu(sb[src1] + di);
      if (i2 >= 64 && v2) xl2 = lrelu(sb[src2] + di);
    }
    float w1 = v1 ? __expf(xl1 - m) : 0.f;
    float w2 = v2 ? __expf(xl2 - m) : 0.f;
#pragma unroll
    for (int v = 0; v < 8; ++v) {
      acc[v]     = fmaf(w1, bs2f(a0[v]), acc[v]);
      acc[8 + v] = fmaf(w1, bs2f(a1[v]), acc[8 + v]);
    }
#pragma unroll
    for (int v = 0; v < 8; ++v) {
      acc[v]     = fmaf(w2, bs2f(b0[v]), acc[v]);
      acc[8 + v] = fmaf(w2, bs2f(b1[v]), acc[8 + v]);
    }
  }
#pragma unroll
  for (int v = 0; v < 16; ++v) {
    acc[v] += __shfl_xor(acc[v], 16);
    acc[v] += __shfl_xor(acc[v], 32);
  }
  if (lane < 16) {
    float4v o0, o1, o2, o3;
#pragma unroll
    for (int v = 0; v < 4; ++v) {
      o0[v] = fmaxf(fmaf(acc[v],      inv, bias[l16 * 16 + v]),      0.f);
      o1[v] = fmaxf(fmaf(acc[4 + v],  inv, bias[l16 * 16 + 4 + v]),  0.f);
      o2[v] = fmaxf(fmaf(acc[8 + v],  inv, bias[l16 * 16 + 8 + v]),  0.f);
      o3[v] = fmaxf(fmaf(acc[12 + v], inv, bias[l16 * 16 + 12 + v]), 0.f);
    }
    float* op = outf + (size_t)dst * 256 + l16 * 16;
    *(float4v*)op        = o0;
    *(float4v*)(op + 4)  = o1;
    *(float4v*)(op + 8)  = o2;
    *(float4v*)(op + 12) = o3;
  }
}

// ---------------- fused softmax + aggregation + head dots, layer b ----------------
// h f32 [NP,128]; same uniform-trip-count fix.

__launch_bounds__(256)
__global__ void agg_b(const float* __restrict__ h, const int* __restrict__ src_perm,
                      const int* __restrict__ row_ptr, const float* __restrict__ sb,
                      const float* __restrict__ db, const float* __restrict__ bias,
                      const float* __restrict__ Wout, float* __restrict__ u,
                      float* __restrict__ v_out) {
  int gid = blockIdx.x * blockDim.x + threadIdx.x;
  int dst = gid >> 6, lane = gid & 63;
  if (dst >= NP) return;
  int g = lane >> 4, l16 = lane & 15;
  int s = row_ptr[dst], deg = row_ptr[dst + 1] - s;
  float di = db[dst];
  // phase 1
  float m = -1e30f, ssum = 0.f, x0 = -1e30f;
  for (int c0 = 0; c0 < deg; c0 += 64) {
    int idx = c0 + lane;
    float x = -1e30f;
    if (idx < deg) x = lrelu(sb[src_perm[s + idx]] + di);
    if (c0 == 0) x0 = x;
    float cm = x;
#pragma unroll
    for (int o = 32; o; o >>= 1) cm = fmaxf(cm, __shfl_xor(cm, o));
    float nm = fmaxf(m, cm);
    float ex = (idx < deg) ? __expf(x - nm) : 0.f;
#pragma unroll
    for (int o = 32; o; o >>= 1) ex += __shfl_xor(ex, o);
    ssum = ssum * __expf(m - nm) + ex;
    m = nm;
  }
  float inv = 1.0f / ssum;
  // phase 2: uniform trip count
  float acc[8];
#pragma unroll
  for (int v = 0; v < 8; ++v) acc[v] = 0.f;
  for (int it0 = 0; it0 < deg; it0 += 8) {
    int it = it0 + g;
    int i2 = it + 4;
    bool v1 = (it < deg), v2 = (i2 < deg);
    int src1 = v1 ? src_perm[s + it] : src_perm[s];
    int src2 = v2 ? src_perm[s + i2] : src_perm[s];
    const float* p1 = h + (size_t)src1 * 128 + l16 * 8;
    const float* p2 = h + (size_t)src2 * 128 + l16 * 8;
    float4v a0 = *(const float4v*)p1;
    float4v a1 = *(const float4v*)(p1 + 4);
    float4v b0 = *(const float4v*)p2;
    float4v b1 = *(const float4v*)(p2 + 4);
    float xl1 = __shfl(x0, it & 63);
    float xl2 = __shfl(x0, i2 & 63);
    if (deg > 64) {
      if (it >= 64 && v1) xl1 = lrelu(sb[src1] + di);
      if (i2 >= 64 && v2) xl2 = lrelu(sb[src2] + di);
    }
    float w1 = v1 ? __expf(xl1 - m) : 0.f;
    float w2 = v2 ? __expf(xl2 - m) : 0.f;
#pragma unroll
    for (int v = 0; v < 4; ++v) {
      acc[v]     = fmaf(w1, a0[v], acc[v]);
      acc[4 + v] = fmaf(w1, a1[v], acc[4 + v]);
    }
#pragma unroll
    for (int v = 0; v < 4; ++v) {
      acc[v]     = fmaf(w2, b0[v], acc[v]);
      acc[4 + v] = fmaf(w2, b1[v], acc[4 + v]);
    }
  }
#pragma unroll
  for (int v = 0; v < 8; ++v) {
    acc[v] += __shfl_xor(acc[v], 16);
    acc[v] += __shfl_xor(acc[v], 32);
  }
  // head dots on lanes 0-15 (each holds cols l16*8 .. +8)
  float su = 0.f, sv = 0.f;
  if (lane < 16) {
#pragma unroll
    for (int v = 0; v < 8; ++v) {
      float o = fmaf(acc[v], inv, bias[l16 * 8 + v]);
      su = fmaf(o, Wout[l16 * 8 + v], su);
      sv = fmaf(o, Wout[128 + l16 * 8 + v], sv);
    }
  }
#pragma unroll
  for (int o = 1; o < 16; o <<= 1) {
    su += __shfl_xor(su, o);
    sv += __shfl_xor(sv, o);
  }
  if (lane == 0) { u[dst] = su; v_out[dst] = sv; }
}

// ---------------- output ----------------

__global__ void out_kernel(const int* __restrict__ mask, const float* __restrict__ u,
                           const float* __restrict__ v, const float* __restrict__ bout,
                           float* __restrict__ out) {
  int p = blockIdx.x * blockDim.x + threadIdx.x;
  if (p >= NPAIR) return;
  int a = mask[2 * p], b = mask[2 * p + 1];
  float logit = u[a] + v[b] + bout[0];
  out[p] = 1.0f / (1.0f + __expf(-logit));
}

// ---------------- launch ----------------

extern "C" void kernel_launch(void* const* d_in, const int* in_sizes, int n_in,
                              void* d_out, int out_size, void* d_ws, size_t ws_size,
                              hipStream_t stream) {
  const float* xp   = (const float*)d_in[0];
  const int*   ei   = (const int*)d_in[5];          // ei_ppi (2, E_PPI)
  const int*   mask = (const int*)d_in[6];
  const float* Wa2  = (const float*)d_in[7]  + 2 * F * H;   // Wa[2]  [128,256]
  const float* asa  = (const float*)d_in[8]  + 2 * H;
  const float* ada  = (const float*)d_in[9]  + 2 * H;
  const float* ba   = (const float*)d_in[10] + 2 * H;
  const float* Wb2  = (const float*)d_in[11] + 2 * H * F;   // Wb[2]  [256,128]
  const float* asb  = (const float*)d_in[12] + 2 * F;
  const float* adb  = (const float*)d_in[13] + 2 * F;
  const float* bb   = (const float*)d_in[14] + 2 * F;
  const float* Wout = (const float*)d_in[21];
  const float* bout = (const float*)d_in[22];
  float* out = (float*)d_out;

  char* ws = (char*)d_ws;
  size_t off = 0;
  auto alloc = [&](size_t bytes) {
    void* p = ws + off;
    off = (off + bytes + 255) & ~(size_t)255;
    return p;
  };
  short* h1b     = (short*)alloc((size_t)NP * H * 2);      // bf16 [50000,256]
  float* hpf     = (float*)alloc((size_t)NP * H * 4);      // f32 relu'd layer-a out
  float* h2f     = (float*)alloc((size_t)NP * F * 4);      // f32 [50000,128]
  int*   src_perm= (int*)alloc((size_t)ET * 4);
  int*   row_ptr = (int*)alloc((size_t)NSCAN * 4);
  int*   cursor  = (int*)alloc((size_t)NP * 4);
  int*   deg     = (int*)alloc((size_t)NSCAN * 4);
  int*   bsum    = (int*)alloc((size_t)NB_SCAN * 4);
  float* sb      = (float*)alloc((size_t)NP * 4);
  float* db      = (float*)alloc((size_t)NP * 4);
  float* u       = (float*)alloc((size_t)NP * 4);
  float* v       = (float*)alloc((size_t)NP * 4);
  short* BaH     = (short*)alloc((size_t)F * H * 2);       // packed Wa2 hi
  short* BaL     = (short*)alloc((size_t)F * H * 2);       // packed Wa2 lo
  short* BbH     = (short*)alloc((size_t)H * F * 2);       // packed Wb2 hi
  short* BbL     = (short*)alloc((size_t)H * F * 2);       // packed Wb2 lo

  const int* src_idx = ei;
  const int* dst_idx = ei + E_PPI;

  // CSR over ppi edges + self loops (shared by both layers)
  hipMemsetAsync(deg, 0, (size_t)NSCAN * 4, stream);
  deg_kernel<<<(ET + 255) / 256, 256, 0, stream>>>(dst_idx, deg);
  scan_partial<<<NB_SCAN, 1024, 0, stream>>>(deg, row_ptr, bsum);
  scan_sums<<<1, 64, 0, stream>>>(bsum);
  scan_add<<<(NSCAN + 255) / 256, 256, 0, stream>>>(row_ptr, cursor, bsum);
  fill_kernel<<<(ET + 255) / 256, 256, 0, stream>>>(src_idx, dst_idx, cursor, src_perm);

  // pack weights into MFMA fragment order (hi + lo)
  pack_B<F, H><<<(16 * 4 * 64 + 255) / 256, 256, 0, stream>>>(Wa2, BaH, BaL);
  pack_B<H, F><<<(8 * 8 * 64 + 255) / 256, 256, 0, stream>>>(Wb2, BbH, BbL);

  int node_wave_blocks = NP / 4;   // wave per node, 4 waves/block

  // ---- layer a: h1 = xp @ Wa2 (bf16 out, fused dots), fused softmax+agg+relu (f32 out) ----
  gemm_mfma<F, H, true><<<NP / 16, 256, 0, stream>>>(xp, BaH, BaL, h1b, asa, ada, sb, db);
  agg_a<<<node_wave_blocks, 256, 0, stream>>>(h1b, src_perm, row_ptr, sb, db, ba, hpf);

  // ---- layer b: h2 = hp @ Wb2 (f32 out, fused dots), fused softmax+agg+head ----
  gemm_mfma<H, F, false><<<NP / 16, 256, 0, stream>>>(hpf, BbH, BbL, h2f, asb, adb, sb, db);
  agg_b<<<node_wave_blocks, 256, 0, stream>>>(h2f, src_perm, row_ptr, sb, db, bb, Wout, u, v);

  // ---- link-prediction head ----
  out_kernel<<<(NPAIR + 255) / 256, 256, 0, stream>>>(mask, u, v, bout, out);
}

// Round 7
// 393.638 us; speedup vs baseline: 1.9640x; 1.0684x over previous
//
#include <hip/hip_runtime.h>
#include <hip/hip_bf16.h>
#include <math.h>

#define NP 50000
#define F 128
#define H 256
#define E_PPI 800000
#define ET (E_PPI + NP)   // edges + self loops
#define NPAIR 200000
#define NSCAN (NP + 1)
#define NB_SCAN ((NSCAN + 1023) / 1024)   // 49

typedef __attribute__((ext_vector_type(8))) short short8v;
typedef __attribute__((ext_vector_type(4))) float float4v;

__device__ __forceinline__ short f2bs(float f) {  // f32 -> bf16 bits, RNE
  unsigned u = __builtin_bit_cast(unsigned, f);
  unsigned r = (u + 0x7FFFu + ((u >> 16) & 1u)) >> 16;
  return (short)r;
}
__device__ __forceinline__ float bs2f(short s) {
  unsigned u = ((unsigned)(unsigned short)s) << 16;
  return __builtin_bit_cast(float, u);
}
__device__ __forceinline__ float lrelu(float t) { return (t > 0.f) ? t : 0.2f * t; }

// ---------------- CSR build ----------------

__global__ void deg_kernel(const int* __restrict__ dst_idx, int* __restrict__ deg) {
  int k = blockIdx.x * blockDim.x + threadIdx.x;
  if (k >= ET) return;
  int d = (k < E_PPI) ? dst_idx[k] : (k - E_PPI);
  atomicAdd(&deg[d], 1);
}

__global__ void scan_partial(const int* __restrict__ deg, int* __restrict__ row_ptr,
                             int* __restrict__ bsum) {
  __shared__ int buf[1024];
  int tid = threadIdx.x;
  int idx = blockIdx.x * 1024 + tid;
  int v = (idx < NSCAN) ? deg[idx] : 0;   // deg[NP] stays 0
  buf[tid] = v;
  __syncthreads();
  for (int off = 1; off < 1024; off <<= 1) {
    int t = (tid >= off) ? buf[tid - off] : 0;
    __syncthreads();
    buf[tid] += t;
    __syncthreads();
  }
  if (idx < NSCAN) row_ptr[idx] = buf[tid] - v;     // exclusive within block
  if (tid == 1023) bsum[blockIdx.x] = buf[1023];
}

__global__ void scan_sums(int* __restrict__ bsum) {
  int lane = threadIdx.x;
  int v = (lane < NB_SCAN) ? bsum[lane] : 0;
  for (int off = 1; off < 64; off <<= 1) {
    int t = __shfl_up(v, off);
    if (lane >= off) v += t;
  }
  int ex = __shfl_up(v, 1);
  if (lane == 0) ex = 0;
  if (lane < NB_SCAN) bsum[lane] = ex;
}

__global__ void scan_add(int* __restrict__ row_ptr, int* __restrict__ cursor,
                         const int* __restrict__ bsum) {
  int idx = blockIdx.x * blockDim.x + threadIdx.x;
  if (idx >= NSCAN) return;
  int v = row_ptr[idx] + bsum[idx >> 10];
  row_ptr[idx] = v;
  if (idx < NP) cursor[idx] = v;
}

__global__ void fill_kernel(const int* __restrict__ src_idx, const int* __restrict__ dst_idx,
                            int* __restrict__ cursor, int* __restrict__ src_perm) {
  int k = blockIdx.x * blockDim.x + threadIdx.x;
  if (k >= ET) return;
  int s, d;
  if (k < E_PPI) { s = src_idx[k]; d = dst_idx[k]; }
  else           { s = d = k - E_PPI; }
  int pos = atomicAdd(&cursor[d], 1);
  src_perm[pos] = s;
}

// ---------------- weight pack into MFMA fragment order, hi+lo bf16 split ----------------

template<int K, int N>
__device__ __forceinline__ void pack_one(const float* __restrict__ B, short* __restrict__ Bh,
                                         short* __restrict__ Bl, int idx) {
  constexpr int KB = K / 32;
  int lane = idx & 63;
  int rest = idx >> 6;
  int kb = rest % KB;
  int tile = rest / KB;
  int n = tile * 16 + (lane & 15);
  int k0 = kb * 32 + (lane >> 4) * 8;
  size_t base = (size_t)idx * 8;
#pragma unroll
  for (int j = 0; j < 8; ++j) {
    float x = B[(size_t)(k0 + j) * N + n];
    short hi = f2bs(x);
    Bh[base + j] = hi;
    Bl[base + j] = f2bs(x - bs2f(hi));
  }
}

__global__ void pack_both(const float* __restrict__ Wa, const float* __restrict__ Wb,
                          short* __restrict__ BaH, short* __restrict__ BaL,
                          short* __restrict__ BbH, short* __restrict__ BbL) {
  int idx = blockIdx.x * blockDim.x + threadIdx.x;
  if (idx < 4096)      pack_one<F, H>(Wa, BaH, BaL, idx);          // 16 tiles * 4 kb * 64
  else if (idx < 8192) pack_one<H, F>(Wb, BbH, BbL, idx - 4096);   // 8 tiles * 8 kb * 64
}

// ---------------- MFMA GEMM + fused attention dots ----------------
// AF32: A f32 -> (hi,lo) split, 3 MFMAs/tile. else A bf16, 2 MFMAs/tile (B split).

template<int K, int N, bool AF32>
__launch_bounds__(256)
__global__ void gemm_mfma(const void* __restrict__ Av, const short* __restrict__ Bh,
                          const short* __restrict__ Bl, short* __restrict__ Cb,
                          const float* __restrict__ a_s, const float* __restrict__ a_d,
                          float* __restrict__ sb, float* __restrict__ db) {
  constexpr int KB = K / 32;
  constexpr int TPW = N / 64;   // 16-col tiles per wave
  __shared__ float sred[4][16];
  __shared__ float dred[4][16];
  int lane = threadIdx.x & 63, wave = threadIdx.x >> 6;
  int ln16 = lane & 15, quad = lane >> 4;
  int m0 = blockIdx.x * 16;
  float4v acc[TPW];
#pragma unroll
  for (int t = 0; t < TPW; ++t) acc[t] = (float4v)0.f;
#pragma unroll
  for (int kb = 0; kb < KB; ++kb) {
    int ka = kb * 32 + quad * 8;
    short8v ah, al;
    if constexpr (AF32) {
      const float* ap = (const float*)Av + (size_t)(m0 + ln16) * K + ka;
      float4v a0 = *(const float4v*)ap;
      float4v a1 = *(const float4v*)(ap + 4);
#pragma unroll
      for (int j = 0; j < 4; ++j) {
        short h0 = f2bs(a0[j]); ah[j] = h0;     al[j] = f2bs(a0[j] - bs2f(h0));
        short h1 = f2bs(a1[j]); ah[4 + j] = h1; al[4 + j] = f2bs(a1[j] - bs2f(h1));
      }
    } else {
      ah = *(const short8v*)((const short*)Av + (size_t)(m0 + ln16) * K + ka);
    }
#pragma unroll
    for (int t = 0; t < TPW; ++t) {
      int tile = wave * TPW + t;
      size_t boff = ((size_t)(tile * KB + kb) * 64 + lane) * 8;
      short8v bh = *(const short8v*)(Bh + boff);
      short8v bl = *(const short8v*)(Bl + boff);
      acc[t] = __builtin_amdgcn_mfma_f32_16x16x32_bf16(ah, bh, acc[t], 0, 0, 0);
      if constexpr (AF32)
        acc[t] = __builtin_amdgcn_mfma_f32_16x16x32_bf16(al, bh, acc[t], 0, 0, 0);
      acc[t] = __builtin_amdgcn_mfma_f32_16x16x32_bf16(ah, bl, acc[t], 0, 0, 0);
    }
  }
  // store h (bf16); C/D layout: col = lane&15, row = quad*4 + reg
#pragma unroll
  for (int t = 0; t < TPW; ++t) {
    int cc = (wave * TPW + t) * 16 + ln16;
#pragma unroll
    for (int r = 0; r < 4; ++r) {
      int rr = m0 + quad * 4 + r;
      Cb[(size_t)rr * N + cc] = f2bs(acc[t][r]);
    }
  }
  // fused dots over this wave's columns (f32 accs)
  float su[4] = {0.f, 0.f, 0.f, 0.f}, dv[4] = {0.f, 0.f, 0.f, 0.f};
#pragma unroll
  for (int t = 0; t < TPW; ++t) {
    int cc = (wave * TPW + t) * 16 + ln16;
    float as = a_s[cc], ad = a_d[cc];
#pragma unroll
    for (int r = 0; r < 4; ++r) {
      su[r] = fmaf(acc[t][r], as, su[r]);
      dv[r] = fmaf(acc[t][r], ad, dv[r]);
    }
  }
#pragma unroll
  for (int r = 0; r < 4; ++r) {
    for (int off = 1; off < 16; off <<= 1) {
      su[r] += __shfl_xor(su[r], off);
      dv[r] += __shfl_xor(dv[r], off);
    }
  }
  if (ln16 == 0) {
#pragma unroll
    for (int r = 0; r < 4; ++r) {
      sred[wave][quad * 4 + r] = su[r];
      dred[wave][quad * 4 + r] = dv[r];
    }
  }
  __syncthreads();
  if (threadIdx.x < 16) {
    int row = threadIdx.x;
    sb[m0 + row] = sred[0][row] + sred[1][row] + sred[2][row] + sred[3][row];
    db[m0 + row] = dred[0][row] + dred[1][row] + dred[2][row] + dred[3][row];
  }
}

// ---------------- fused softmax + aggregation, layer a ----------------
// Wave per dst. ALL phase-2 trip counts wave-uniform (shfl safety).
// 4 edges per 16-lane group per iteration -> 8 x 16B gathers in flight.

__launch_bounds__(256)
__global__ void agg_a(const short* __restrict__ h, const int* __restrict__ src_perm,
                      const int* __restrict__ row_ptr, const float* __restrict__ sb,
                      const float* __restrict__ db, const float* __restrict__ bias,
                      short* __restrict__ outb) {
  int gid = blockIdx.x * blockDim.x + threadIdx.x;
  int dst = gid >> 6, lane = gid & 63;
  if (dst >= NP) return;
  int g = lane >> 4, l16 = lane & 15;
  int s = row_ptr[dst], deg = row_ptr[dst + 1] - s;
  float di = db[dst];
  // phase 1: lane-parallel online softmax stats; x0 = chunk-0 logits
  float m = -1e30f, ssum = 0.f, x0 = -1e30f;
  for (int c0 = 0; c0 < deg; c0 += 64) {
    int idx = c0 + lane;
    float x = -1e30f;
    if (idx < deg) x = lrelu(sb[src_perm[s + idx]] + di);
    if (c0 == 0) x0 = x;
    float cm = x;
#pragma unroll
    for (int o = 32; o; o >>= 1) cm = fmaxf(cm, __shfl_xor(cm, o));
    float nm = fmaxf(m, cm);
    float ex = (idx < deg) ? __expf(x - nm) : 0.f;
#pragma unroll
    for (int o = 32; o; o >>= 1) ex += __shfl_xor(ex, o);
    ssum = ssum * __expf(m - nm) + ex;
    m = nm;
  }
  float inv = 1.0f / ssum;
  // phase 2: 16 edges per iteration (4 per group), uniform trip count
  float acc[16];
#pragma unroll
  for (int v = 0; v < 16; ++v) acc[v] = 0.f;
  for (int it0 = 0; it0 < deg; it0 += 16) {
    int e[4]; bool vv[4]; int si[4];
#pragma unroll
    for (int j = 0; j < 4; ++j) {
      e[j] = it0 + g + 4 * j;
      vv[j] = e[j] < deg;
      si[j] = vv[j] ? src_perm[s + e[j]] : src_perm[s];
    }
    short8v lo[4], hi[4];
#pragma unroll
    for (int j = 0; j < 4; ++j) {
      const short* p = h + (size_t)si[j] * 256 + l16 * 16;
      lo[j] = *(const short8v*)p;
      hi[j] = *(const short8v*)(p + 8);
    }
    float w[4];
#pragma unroll
    for (int j = 0; j < 4; ++j) {
      float xl = __shfl(x0, e[j] & 63);   // all 64 lanes active
      if (deg > 64) {                     // wave-uniform branch (never taken here)
        if (e[j] >= 64 && vv[j]) xl = lrelu(sb[si[j]] + di);
      }
      w[j] = vv[j] ? __expf(xl - m) : 0.f;
    }
#pragma unroll
    for (int j = 0; j < 4; ++j)
#pragma unroll
      for (int v = 0; v < 8; ++v) {
        acc[v]     = fmaf(w[j], bs2f(lo[j][v]), acc[v]);
        acc[8 + v] = fmaf(w[j], bs2f(hi[j][v]), acc[8 + v]);
      }
  }
#pragma unroll
  for (int v = 0; v < 16; ++v) {
    acc[v] += __shfl_xor(acc[v], 16);
    acc[v] += __shfl_xor(acc[v], 32);
  }
  if (lane < 16) {
    short8v o0, o1;
#pragma unroll
    for (int v = 0; v < 8; ++v) {
      o0[v] = f2bs(fmaxf(fmaf(acc[v],     inv, bias[l16 * 16 + v]),     0.f));
      o1[v] = f2bs(fmaxf(fmaf(acc[8 + v], inv, bias[l16 * 16 + 8 + v]), 0.f));
    }
    short* op = outb + (size_t)dst * 256 + l16 * 16;
    *(short8v*)op       = o0;
    *(short8v*)(op + 8) = o1;
  }
}

// ---------------- fused softmax + aggregation + head dots, layer b ----------------
// h bf16 [NP,128]; 8 edges per group per iteration (covers deg<=32 in one pass).

__launch_bounds__(256)
__global__ void agg_b(const short* __restrict__ h, const int* __restrict__ src_perm,
                      const int* __restrict__ row_ptr, const float* __restrict__ sb,
                      const float* __restrict__ db, const float* __restrict__ bias,
                      const float* __restrict__ Wout, float* __restrict__ u,
                      float* __restrict__ v_out) {
  int gid = blockIdx.x * blockDim.x + threadIdx.x;
  int dst = gid >> 6, lane = gid & 63;
  if (dst >= NP) return;
  int g = lane >> 4, l16 = lane & 15;
  int s = row_ptr[dst], deg = row_ptr[dst + 1] - s;
  float di = db[dst];
  // phase 1
  float m = -1e30f, ssum = 0.f, x0 = -1e30f;
  for (int c0 = 0; c0 < deg; c0 += 64) {
    int idx = c0 + lane;
    float x = -1e30f;
    if (idx < deg) x = lrelu(sb[src_perm[s + idx]] + di);
    if (c0 == 0) x0 = x;
    float cm = x;
#pragma unroll
    for (int o = 32; o; o >>= 1) cm = fmaxf(cm, __shfl_xor(cm, o));
    float nm = fmaxf(m, cm);
    float ex = (idx < deg) ? __expf(x - nm) : 0.f;
#pragma unroll
    for (int o = 32; o; o >>= 1) ex += __shfl_xor(ex, o);
    ssum = ssum * __expf(m - nm) + ex;
    m = nm;
  }
  float inv = 1.0f / ssum;
  // phase 2: 32 edges per iteration (8 per group), uniform trip count
  float acc[8];
#pragma unroll
  for (int v = 0; v < 8; ++v) acc[v] = 0.f;
  for (int it0 = 0; it0 < deg; it0 += 32) {
    int e[8]; bool vv[8]; int si[8];
#pragma unroll
    for (int j = 0; j < 8; ++j) {
      e[j] = it0 + g + 4 * j;
      vv[j] = e[j] < deg;
      si[j] = vv[j] ? src_perm[s + e[j]] : src_perm[s];
    }
    short8v x[8];
#pragma unroll
    for (int j = 0; j < 8; ++j)
      x[j] = *(const short8v*)(h + (size_t)si[j] * 128 + l16 * 8);
    float w[8];
#pragma unroll
    for (int j = 0; j < 8; ++j) {
      float xl = __shfl(x0, e[j] & 63);
      if (deg > 64) {
        if (e[j] >= 64 && vv[j]) xl = lrelu(sb[si[j]] + di);
      }
      w[j] = vv[j] ? __expf(xl - m) : 0.f;
    }
#pragma unroll
    for (int j = 0; j < 8; ++j)
#pragma unroll
      for (int v = 0; v < 8; ++v) acc[v] = fmaf(w[j], bs2f(x[j][v]), acc[v]);
  }
#pragma unroll
  for (int v = 0; v < 8; ++v) {
    acc[v] += __shfl_xor(acc[v], 16);
    acc[v] += __shfl_xor(acc[v], 32);
  }
  // head dots on lanes 0-15 (each holds cols l16*8 .. +8)
  float su = 0.f, sv = 0.f;
  if (lane < 16) {
#pragma unroll
    for (int v = 0; v < 8; ++v) {
      float o = fmaf(acc[v], inv, bias[l16 * 8 + v]);
      su = fmaf(o, Wout[l16 * 8 + v], su);
      sv = fmaf(o, Wout[128 + l16 * 8 + v], sv);
    }
  }
#pragma unroll
  for (int o = 1; o < 16; o <<= 1) {
    su += __shfl_xor(su, o);
    sv += __shfl_xor(sv, o);
  }
  if (lane == 0) { u[dst] = su; v_out[dst] = sv; }
}

// ---------------- output ----------------

__global__ void out_kernel(const int* __restrict__ mask, const float* __restrict__ u,
                           const float* __restrict__ v, const float* __restrict__ bout,
                           float* __restrict__ out) {
  int p = blockIdx.x * blockDim.x + threadIdx.x;
  if (p >= NPAIR) return;
  int a = mask[2 * p], b = mask[2 * p + 1];
  float logit = u[a] + v[b] + bout[0];
  out[p] = 1.0f / (1.0f + __expf(-logit));
}

// ---------------- launch ----------------

extern "C" void kernel_launch(void* const* d_in, const int* in_sizes, int n_in,
                              void* d_out, int out_size, void* d_ws, size_t ws_size,
                              hipStream_t stream) {
  const float* xp   = (const float*)d_in[0];
  const int*   ei   = (const int*)d_in[5];          // ei_ppi (2, E_PPI)
  const int*   mask = (const int*)d_in[6];
  const float* Wa2  = (const float*)d_in[7]  + 2 * F * H;   // Wa[2]  [128,256]
  const float* asa  = (const float*)d_in[8]  + 2 * H;
  const float* ada  = (const float*)d_in[9]  + 2 * H;
  const float* ba   = (const float*)d_in[10] + 2 * H;
  const float* Wb2  = (const float*)d_in[11] + 2 * H * F;   // Wb[2]  [256,128]
  const float* asb  = (const float*)d_in[12] + 2 * F;
  const float* adb  = (const float*)d_in[13] + 2 * F;
  const float* bb   = (const float*)d_in[14] + 2 * F;
  const float* Wout = (const float*)d_in[21];
  const float* bout = (const float*)d_in[22];
  float* out = (float*)d_out;

  char* ws = (char*)d_ws;
  size_t off = 0;
  auto alloc = [&](size_t bytes) {
    void* p = ws + off;
    off = (off + bytes + 255) & ~(size_t)255;
    return p;
  };
  short* h1b     = (short*)alloc((size_t)NP * H * 2);      // bf16 [50000,256]
  short* hpb     = (short*)alloc((size_t)NP * H * 2);      // bf16 relu'd layer-a out
  short* h2b     = (short*)alloc((size_t)NP * F * 2);      // bf16 [50000,128]
  int*   src_perm= (int*)alloc((size_t)ET * 4);
  int*   row_ptr = (int*)alloc((size_t)NSCAN * 4);
  int*   cursor  = (int*)alloc((size_t)NP * 4);
  int*   deg     = (int*)alloc((size_t)NSCAN * 4);
  int*   bsum    = (int*)alloc((size_t)NB_SCAN * 4);
  float* sb      = (float*)alloc((size_t)NP * 4);
  float* db      = (float*)alloc((size_t)NP * 4);
  float* u       = (float*)alloc((size_t)NP * 4);
  float* v       = (float*)alloc((size_t)NP * 4);
  short* BaH     = (short*)alloc((size_t)F * H * 2);       // packed Wa2 hi
  short* BaL     = (short*)alloc((size_t)F * H * 2);       // packed Wa2 lo
  short* BbH     = (short*)alloc((size_t)H * F * 2);       // packed Wb2 hi
  short* BbL     = (short*)alloc((size_t)H * F * 2);       // packed Wb2 lo

  const int* src_idx = ei;
  const int* dst_idx = ei + E_PPI;

  // CSR over ppi edges + self loops (shared by both layers)
  hipMemsetAsync(deg, 0, (size_t)NSCAN * 4, stream);
  deg_kernel<<<(ET + 255) / 256, 256, 0, stream>>>(dst_idx, deg);
  scan_partial<<<NB_SCAN, 1024, 0, stream>>>(deg, row_ptr, bsum);
  scan_sums<<<1, 64, 0, stream>>>(bsum);
  scan_add<<<(NSCAN + 255) / 256, 256, 0, stream>>>(row_ptr, cursor, bsum);
  fill_kernel<<<(ET + 255) / 256, 256, 0, stream>>>(src_idx, dst_idx, cursor, src_perm);

  // pack both weight matrices (hi + lo) in one dispatch
  pack_both<<<8192 / 256, 256, 0, stream>>>(Wa2, Wb2, BaH, BaL, BbH, BbL);

  int node_wave_blocks = NP / 4;   // wave per node, 4 waves/block

  // ---- layer a: h1 = xp @ Wa2 (bf16, fused dots), fused softmax+agg+relu (bf16) ----
  gemm_mfma<F, H, true><<<NP / 16, 256, 0, stream>>>(xp, BaH, BaL, h1b, asa, ada, sb, db);
  agg_a<<<node_wave_blocks, 256, 0, stream>>>(h1b, src_perm, row_ptr, sb, db, ba, hpb);

  // ---- layer b: h2 = hp @ Wb2 (bf16, fused dots), fused softmax+agg+head ----
  gemm_mfma<H, F, false><<<NP / 16, 256, 0, stream>>>(hpb, BbH, BbL, h2b, asb, adb, sb, db);
  agg_b<<<node_wave_blocks, 256, 0, stream>>>(h2b, src_perm, row_ptr, sb, db, bb, Wout, u, v);

  // ---- link-prediction head ----
  out_kernel<<<(NPAIR + 255) / 256, 256, 0, stream>>>(mask, u, v, bout, out);
}

// Round 8
// 373.880 us; speedup vs baseline: 2.0677x; 1.0528x over previous
//
#include <hip/hip_runtime.h>
#include <hip/hip_bf16.h>
#include <math.h>

#define NP 50000
#define F 128
#define H 256
#define E_PPI 800000
#define ET (E_PPI + NP)   // edges + self loops
#define NPAIR 200000
#define NSCAN (NP + 1)
#define NB_SCAN ((NSCAN + 1023) / 1024)   // 49
#define FILL_BLOCKS ((ET + 255) / 256)

typedef __attribute__((ext_vector_type(8))) short short8v;
typedef __attribute__((ext_vector_type(4))) float float4v;
typedef __attribute__((ext_vector_type(2))) float float2v;
typedef __attribute__((ext_vector_type(4))) unsigned int uint4v;

__device__ __forceinline__ short f2bs(float f) {  // f32 -> bf16 bits, RNE
  unsigned u = __builtin_bit_cast(unsigned, f);
  unsigned r = (u + 0x7FFFu + ((u >> 16) & 1u)) >> 16;
  return (short)r;
}
__device__ __forceinline__ float bs2f(short s) {
  unsigned u = ((unsigned)(unsigned short)s) << 16;
  return __builtin_bit_cast(float, u);
}
__device__ __forceinline__ float lrelu(float t) { return (t > 0.f) ? t : 0.2f * t; }

// packed helpers: dword of 2 bf16 -> float2; packed fma (v_pk_fma_f32)
__device__ __forceinline__ float2v bf2x2(unsigned d) {
  float2v f;
  f.x = __builtin_bit_cast(float, d << 16);
  f.y = __builtin_bit_cast(float, d & 0xFFFF0000u);
  return f;
}
__device__ __forceinline__ float2v pkfma(float2v a, float2v b, float2v c) {
#if __has_builtin(__builtin_elementwise_fma)
  return __builtin_elementwise_fma(a, b, c);
#else
  float2v r; r.x = fmaf(a.x, b.x, c.x); r.y = fmaf(a.y, b.y, c.y); return r;
#endif
}

// ---------------- CSR build ----------------

__global__ void deg_kernel(const int* __restrict__ dst_idx, int* __restrict__ deg) {
  int k = blockIdx.x * blockDim.x + threadIdx.x;
  if (k >= ET) return;
  int d = (k < E_PPI) ? dst_idx[k] : (k - E_PPI);
  atomicAdd(&deg[d], 1);
}

__global__ void scan_partial(const int* __restrict__ deg, int* __restrict__ row_ptr,
                             int* __restrict__ bsum) {
  __shared__ int buf[1024];
  int tid = threadIdx.x;
  int idx = blockIdx.x * 1024 + tid;
  int v = (idx < NSCAN) ? deg[idx] : 0;   // deg[NP] stays 0
  buf[tid] = v;
  __syncthreads();
  for (int off = 1; off < 1024; off <<= 1) {
    int t = (tid >= off) ? buf[tid - off] : 0;
    __syncthreads();
    buf[tid] += t;
    __syncthreads();
  }
  if (idx < NSCAN) row_ptr[idx] = buf[tid] - v;     // exclusive within block
  if (tid == 1023) bsum[blockIdx.x] = buf[1023];
}

// merged: per-block redundant wave-scan of the 49 block sums + offset add + cursor init
__global__ void scan_add(int* __restrict__ row_ptr, int* __restrict__ cursor,
                         const int* __restrict__ bsum) {
  __shared__ int soff[64];
  int tid = threadIdx.x;
  if (tid < 64) {
    int v = (tid < NB_SCAN) ? bsum[tid] : 0;
    for (int off = 1; off < 64; off <<= 1) {
      int t = __shfl_up(v, off);
      if (tid >= off) v += t;
    }
    int ex = __shfl_up(v, 1);
    if (tid == 0) ex = 0;
    soff[tid] = ex;
  }
  __syncthreads();
  int idx = blockIdx.x * blockDim.x + tid;
  if (idx >= NSCAN) return;
  int v = row_ptr[idx] + soff[idx >> 10];
  row_ptr[idx] = v;
  if (idx < NP) cursor[idx] = v;
}

// ---------------- weight pack into MFMA fragment order, hi+lo bf16 split ----------------

template<int K, int N>
__device__ __forceinline__ void pack_one(const float* __restrict__ B, short* __restrict__ Bh,
                                         short* __restrict__ Bl, int idx) {
  constexpr int KB = K / 32;
  int lane = idx & 63;
  int rest = idx >> 6;
  int kb = rest % KB;
  int tile = rest / KB;
  int n = tile * 16 + (lane & 15);
  int k0 = kb * 32 + (lane >> 4) * 8;
  size_t base = (size_t)idx * 8;
#pragma unroll
  for (int j = 0; j < 8; ++j) {
    float x = B[(size_t)(k0 + j) * N + n];
    short hi = f2bs(x);
    Bh[base + j] = hi;
    Bl[base + j] = f2bs(x - bs2f(hi));
  }
}

// fused: CSR fill (blocks [0, FILL_BLOCKS)) + both weight packs (32 extra blocks)
__global__ void fill_pack(const int* __restrict__ src_idx, const int* __restrict__ dst_idx,
                          int* __restrict__ cursor, int* __restrict__ src_perm,
                          const float* __restrict__ Wa, const float* __restrict__ Wb,
                          short* __restrict__ BaH, short* __restrict__ BaL,
                          short* __restrict__ BbH, short* __restrict__ BbL) {
  int b = blockIdx.x;
  if (b < FILL_BLOCKS) {
    int k = b * 256 + threadIdx.x;
    if (k >= ET) return;
    int s, d;
    if (k < E_PPI) { s = src_idx[k]; d = dst_idx[k]; }
    else           { s = d = k - E_PPI; }
    int pos = atomicAdd(&cursor[d], 1);
    src_perm[pos] = s;
  } else {
    int idx = (b - FILL_BLOCKS) * 256 + threadIdx.x;
    if (idx < 4096)      pack_one<F, H>(Wa, BaH, BaL, idx);          // 16 tiles * 4 kb * 64
    else if (idx < 8192) pack_one<H, F>(Wb, BbH, BbL, idx - 4096);   // 8 tiles * 8 kb * 64
  }
}

// ---------------- MFMA GEMM + fused attention dots ----------------
// AF32: A f32 -> (hi,lo) split, 3 MFMAs/tile. else A bf16, 2 MFMAs/tile (B split).

template<int K, int N, bool AF32>
__launch_bounds__(256)
__global__ void gemm_mfma(const void* __restrict__ Av, const short* __restrict__ Bh,
                          const short* __restrict__ Bl, short* __restrict__ Cb,
                          const float* __restrict__ a_s, const float* __restrict__ a_d,
                          float* __restrict__ sb, float* __restrict__ db) {
  constexpr int KB = K / 32;
  constexpr int TPW = N / 64;   // 16-col tiles per wave
  __shared__ float sred[4][16];
  __shared__ float dred[4][16];
  int lane = threadIdx.x & 63, wave = threadIdx.x >> 6;
  int ln16 = lane & 15, quad = lane >> 4;
  int m0 = blockIdx.x * 16;
  float4v acc[TPW];
#pragma unroll
  for (int t = 0; t < TPW; ++t) acc[t] = (float4v)0.f;
#pragma unroll
  for (int kb = 0; kb < KB; ++kb) {
    int ka = kb * 32 + quad * 8;
    short8v ah, al;
    if constexpr (AF32) {
      const float* ap = (const float*)Av + (size_t)(m0 + ln16) * K + ka;
      float4v a0 = *(const float4v*)ap;
      float4v a1 = *(const float4v*)(ap + 4);
#pragma unroll
      for (int j = 0; j < 4; ++j) {
        short h0 = f2bs(a0[j]); ah[j] = h0;     al[j] = f2bs(a0[j] - bs2f(h0));
        short h1 = f2bs(a1[j]); ah[4 + j] = h1; al[4 + j] = f2bs(a1[j] - bs2f(h1));
      }
    } else {
      ah = *(const short8v*)((const short*)Av + (size_t)(m0 + ln16) * K + ka);
    }
#pragma unroll
    for (int t = 0; t < TPW; ++t) {
      int tile = wave * TPW + t;
      size_t boff = ((size_t)(tile * KB + kb) * 64 + lane) * 8;
      short8v bh = *(const short8v*)(Bh + boff);
      short8v bl = *(const short8v*)(Bl + boff);
      acc[t] = __builtin_amdgcn_mfma_f32_16x16x32_bf16(ah, bh, acc[t], 0, 0, 0);
      if constexpr (AF32)
        acc[t] = __builtin_amdgcn_mfma_f32_16x16x32_bf16(al, bh, acc[t], 0, 0, 0);
      acc[t] = __builtin_amdgcn_mfma_f32_16x16x32_bf16(ah, bl, acc[t], 0, 0, 0);
    }
  }
  // store h (bf16); C/D layout: col = lane&15, row = quad*4 + reg
#pragma unroll
  for (int t = 0; t < TPW; ++t) {
    int cc = (wave * TPW + t) * 16 + ln16;
#pragma unroll
    for (int r = 0; r < 4; ++r) {
      int rr = m0 + quad * 4 + r;
      Cb[(size_t)rr * N + cc] = f2bs(acc[t][r]);
    }
  }
  // fused dots over this wave's columns (f32 accs)
  float su[4] = {0.f, 0.f, 0.f, 0.f}, dv[4] = {0.f, 0.f, 0.f, 0.f};
#pragma unroll
  for (int t = 0; t < TPW; ++t) {
    int cc = (wave * TPW + t) * 16 + ln16;
    float as = a_s[cc], ad = a_d[cc];
#pragma unroll
    for (int r = 0; r < 4; ++r) {
      su[r] = fmaf(acc[t][r], as, su[r]);
      dv[r] = fmaf(acc[t][r], ad, dv[r]);
    }
  }
#pragma unroll
  for (int r = 0; r < 4; ++r) {
    for (int off = 1; off < 16; off <<= 1) {
      su[r] += __shfl_xor(su[r], off);
      dv[r] += __shfl_xor(dv[r], off);
    }
  }
  if (ln16 == 0) {
#pragma unroll
    for (int r = 0; r < 4; ++r) {
      sred[wave][quad * 4 + r] = su[r];
      dred[wave][quad * 4 + r] = dv[r];
    }
  }
  __syncthreads();
  if (threadIdx.x < 16) {
    int row = threadIdx.x;
    sb[m0 + row] = sred[0][row] + sred[1][row] + sred[2][row] + sred[3][row];
    db[m0 + row] = dred[0][row] + dred[1][row] + dred[2][row] + dred[3][row];
  }
}

// ---------------- fused softmax + aggregation, layer a ----------------
// Wave per dst. Phase 1: lane-parallel online softmax + per-edge weight precompute
// (one exp per edge, in w0). Phase 2: 2 edges/iter (half-wave each, 16B/lane),
// unrolled x2, packed bf16->f32 convert + v_pk_fma_f32. All shfls at uniform
// trip counts (e<64 test is uniform since it0 % 4 == 0).

__launch_bounds__(256)
__global__ void agg_a(const short* __restrict__ h, const int* __restrict__ src_perm,
                      const int* __restrict__ row_ptr, const float* __restrict__ sb,
                      const float* __restrict__ db, const float* __restrict__ bias,
                      short* __restrict__ outb) {
  int gid = blockIdx.x * blockDim.x + threadIdx.x;
  int dst = gid >> 6, lane = gid & 63;
  if (dst >= NP) return;
  int half = lane >> 5, l32 = lane & 31;
  int s = row_ptr[dst], deg = row_ptr[dst + 1] - s;
  float di = db[dst];
  // phase 1
  float m = -1e30f, ssum = 0.f, x0 = -1e30f;
  for (int c0 = 0; c0 < deg; c0 += 64) {
    int idx = c0 + lane;
    float x = -1e30f;
    if (idx < deg) x = lrelu(sb[src_perm[s + idx]] + di);
    if (c0 == 0) x0 = x;
    float cm = x;
#pragma unroll
    for (int o = 32; o; o >>= 1) cm = fmaxf(cm, __shfl_xor(cm, o));
    float nm = fmaxf(m, cm);
    float ex = (idx < deg) ? __expf(x - nm) : 0.f;
#pragma unroll
    for (int o = 32; o; o >>= 1) ex += __shfl_xor(ex, o);
    ssum = ssum * __expf(m - nm) + ex;
    m = nm;
  }
  float inv = 1.0f / ssum;
  float w0 = __expf(x0 - m);   // lane i -> weight of edge i (0 for lane >= deg)
  // phase 2
  float2v acc2[4];
#pragma unroll
  for (int k = 0; k < 4; ++k) acc2[k] = (float2v)0.f;
  for (int it0 = 0; it0 < deg; it0 += 4) {
    int e1 = it0 + half, e2 = it0 + 2 + half;
    bool v1 = (e1 < deg), v2 = (e2 < deg);
    int s1 = v1 ? src_perm[s + e1] : src_perm[s];
    int s2 = v2 ? src_perm[s + e2] : src_perm[s];
    short8v xa = *(const short8v*)(h + (size_t)s1 * 256 + l32 * 8);
    short8v xb = *(const short8v*)(h + (size_t)s2 * 256 + l32 * 8);
    float w1 = __shfl(w0, e1 & 63);
    float w2 = __shfl(w0, e2 & 63);
    if (deg > 64) {   // wave-uniform; e>=64 test uniform (it0 % 4 == 0)
      if (e1 >= 64 && v1) w1 = __expf(lrelu(sb[s1] + di) - m);
      if (e2 >= 64 && v2) w2 = __expf(lrelu(sb[s2] + di) - m);
    }
    w1 = v1 ? w1 : 0.f;
    w2 = v2 ? w2 : 0.f;
    uint4v da = __builtin_bit_cast(uint4v, xa);
    uint4v dbv = __builtin_bit_cast(uint4v, xb);
    float2v W1 = {w1, w1}, W2 = {w2, w2};
#pragma unroll
    for (int k = 0; k < 4; ++k) {
      acc2[k] = pkfma(bf2x2(da[k]), W1, acc2[k]);
      acc2[k] = pkfma(bf2x2(dbv[k]), W2, acc2[k]);
    }
  }
#pragma unroll
  for (int k = 0; k < 4; ++k) {
    acc2[k].x += __shfl_xor(acc2[k].x, 32);
    acc2[k].y += __shfl_xor(acc2[k].y, 32);
  }
  if (half == 0) {
    short8v o;
#pragma unroll
    for (int k = 0; k < 4; ++k) {
      o[2 * k]     = f2bs(fmaxf(fmaf(acc2[k].x, inv, bias[l32 * 8 + 2 * k]),     0.f));
      o[2 * k + 1] = f2bs(fmaxf(fmaf(acc2[k].y, inv, bias[l32 * 8 + 2 * k + 1]), 0.f));
    }
    *(short8v*)(outb + (size_t)dst * 256 + l32 * 8) = o;
  }
}

// ---------------- fused softmax + aggregation + head dots, layer b ----------------
// h bf16 [NP,128]; 16 lanes/edge, 8 edges per wave-iteration (2 per group), packed math.

__launch_bounds__(256)
__global__ void agg_b(const short* __restrict__ h, const int* __restrict__ src_perm,
                      const int* __restrict__ row_ptr, const float* __restrict__ sb,
                      const float* __restrict__ db, const float* __restrict__ bias,
                      const float* __restrict__ Wout, float* __restrict__ u,
                      float* __restrict__ v_out) {
  int gid = blockIdx.x * blockDim.x + threadIdx.x;
  int dst = gid >> 6, lane = gid & 63;
  if (dst >= NP) return;
  int g = lane >> 4, l16 = lane & 15;
  int s = row_ptr[dst], deg = row_ptr[dst + 1] - s;
  float di = db[dst];
  // phase 1
  float m = -1e30f, ssum = 0.f, x0 = -1e30f;
  for (int c0 = 0; c0 < deg; c0 += 64) {
    int idx = c0 + lane;
    float x = -1e30f;
    if (idx < deg) x = lrelu(sb[src_perm[s + idx]] + di);
    if (c0 == 0) x0 = x;
    float cm = x;
#pragma unroll
    for (int o = 32; o; o >>= 1) cm = fmaxf(cm, __shfl_xor(cm, o));
    float nm = fmaxf(m, cm);
    float ex = (idx < deg) ? __expf(x - nm) : 0.f;
#pragma unroll
    for (int o = 32; o; o >>= 1) ex += __shfl_xor(ex, o);
    ssum = ssum * __expf(m - nm) + ex;
    m = nm;
  }
  float inv = 1.0f / ssum;
  float w0 = __expf(x0 - m);
  // phase 2: edges it0+g and it0+g+4 per group; e>=64 / it0 tests wave-uniform
  float2v acc2[4];
#pragma unroll
  for (int k = 0; k < 4; ++k) acc2[k] = (float2v)0.f;
  for (int it0 = 0; it0 < deg; it0 += 8) {
    int e1 = it0 + g, e2 = it0 + g + 4;
    bool v1 = (e1 < deg), v2 = (e2 < deg);
    int s1 = v1 ? src_perm[s + e1] : src_perm[s];
    int s2 = v2 ? src_perm[s + e2] : src_perm[s];
    short8v xa = *(const short8v*)(h + (size_t)s1 * 128 + l16 * 8);
    short8v xb = *(const short8v*)(h + (size_t)s2 * 128 + l16 * 8);
    float w1 = __shfl(w0, e1 & 63);
    float w2 = __shfl(w0, e2 & 63);
    if (deg > 64) {
      if (e1 >= 64 && v1) w1 = __expf(lrelu(sb[s1] + di) - m);
      if (e2 >= 64 && v2) w2 = __expf(lrelu(sb[s2] + di) - m);
    }
    w1 = v1 ? w1 : 0.f;
    w2 = v2 ? w2 : 0.f;
    uint4v da = __builtin_bit_cast(uint4v, xa);
    uint4v dbv = __builtin_bit_cast(uint4v, xb);
    float2v W1 = {w1, w1}, W2 = {w2, w2};
#pragma unroll
    for (int k = 0; k < 4; ++k) {
      acc2[k] = pkfma(bf2x2(da[k]), W1, acc2[k]);
      acc2[k] = pkfma(bf2x2(dbv[k]), W2, acc2[k]);
    }
  }
#pragma unroll
  for (int k = 0; k < 4; ++k) {
    acc2[k].x += __shfl_xor(acc2[k].x, 16);
    acc2[k].y += __shfl_xor(acc2[k].y, 16);
    acc2[k].x += __shfl_xor(acc2[k].x, 32);
    acc2[k].y += __shfl_xor(acc2[k].y, 32);
  }
  // head dots on lanes 0-15 (lane l16 holds cols l16*8 .. +8)
  float su = 0.f, sv = 0.f;
  if (lane < 16) {
#pragma unroll
    for (int k = 0; k < 4; ++k) {
      float o0 = fmaf(acc2[k].x, inv, bias[l16 * 8 + 2 * k]);
      float o1 = fmaf(acc2[k].y, inv, bias[l16 * 8 + 2 * k + 1]);
      su = fmaf(o0, Wout[l16 * 8 + 2 * k], su);
      su = fmaf(o1, Wout[l16 * 8 + 2 * k + 1], su);
      sv = fmaf(o0, Wout[128 + l16 * 8 + 2 * k], sv);
      sv = fmaf(o1, Wout[128 + l16 * 8 + 2 * k + 1], sv);
    }
  }
#pragma unroll
  for (int o = 1; o < 16; o <<= 1) {
    su += __shfl_xor(su, o);
    sv += __shfl_xor(sv, o);
  }
  if (lane == 0) { u[dst] = su; v_out[dst] = sv; }
}

// ---------------- output ----------------

__global__ void out_kernel(const int* __restrict__ mask, const float* __restrict__ u,
                           const float* __restrict__ v, const float* __restrict__ bout,
                           float* __restrict__ out) {
  int p = blockIdx.x * blockDim.x + threadIdx.x;
  if (p >= NPAIR) return;
  int a = mask[2 * p], b = mask[2 * p + 1];
  float logit = u[a] + v[b] + bout[0];
  out[p] = 1.0f / (1.0f + __expf(-logit));
}

// ---------------- launch ----------------

extern "C" void kernel_launch(void* const* d_in, const int* in_sizes, int n_in,
                              void* d_out, int out_size, void* d_ws, size_t ws_size,
                              hipStream_t stream) {
  const float* xp   = (const float*)d_in[0];
  const int*   ei   = (const int*)d_in[5];          // ei_ppi (2, E_PPI)
  const int*   mask = (const int*)d_in[6];
  const float* Wa2  = (const float*)d_in[7]  + 2 * F * H;   // Wa[2]  [128,256]
  const float* asa  = (const float*)d_in[8]  + 2 * H;
  const float* ada  = (const float*)d_in[9]  + 2 * H;
  const float* ba   = (const float*)d_in[10] + 2 * H;
  const float* Wb2  = (const float*)d_in[11] + 2 * H * F;   // Wb[2]  [256,128]
  const float* asb  = (const float*)d_in[12] + 2 * F;
  const float* adb  = (const float*)d_in[13] + 2 * F;
  const float* bb   = (const float*)d_in[14] + 2 * F;
  const float* Wout = (const float*)d_in[21];
  const float* bout = (const float*)d_in[22];
  float* out = (float*)d_out;

  char* ws = (char*)d_ws;
  size_t off = 0;
  auto alloc = [&](size_t bytes) {
    void* p = ws + off;
    off = (off + bytes + 255) & ~(size_t)255;
    return p;
  };
  short* h1b     = (short*)alloc((size_t)NP * H * 2);      // bf16 [50000,256]
  short* hpb     = (short*)alloc((size_t)NP * H * 2);      // bf16 relu'd layer-a out
  short* h2b     = (short*)alloc((size_t)NP * F * 2);      // bf16 [50000,128]
  int*   src_perm= (int*)alloc((size_t)ET * 4);
  int*   row_ptr = (int*)alloc((size_t)NSCAN * 4);
  int*   cursor  = (int*)alloc((size_t)NP * 4);
  int*   deg     = (int*)alloc((size_t)NSCAN * 4);
  int*   bsum    = (int*)alloc((size_t)NB_SCAN * 4);
  float* sb      = (float*)alloc((size_t)NP * 4);
  float* db      = (float*)alloc((size_t)NP * 4);
  float* u       = (float*)alloc((size_t)NP * 4);
  float* v       = (float*)alloc((size_t)NP * 4);
  short* BaH     = (short*)alloc((size_t)F * H * 2);       // packed Wa2 hi
  short* BaL     = (short*)alloc((size_t)F * H * 2);       // packed Wa2 lo
  short* BbH     = (short*)alloc((size_t)H * F * 2);       // packed Wb2 hi
  short* BbL     = (short*)alloc((size_t)H * F * 2);       // packed Wb2 lo

  const int* src_idx = ei;
  const int* dst_idx = ei + E_PPI;

  // CSR over ppi edges + self loops (shared by both layers); 10 graph nodes total
  hipMemsetAsync(deg, 0, (size_t)NSCAN * 4, stream);
  deg_kernel<<<(ET + 255) / 256, 256, 0, stream>>>(dst_idx, deg);
  scan_partial<<<NB_SCAN, 1024, 0, stream>>>(deg, row_ptr, bsum);
  scan_add<<<(NSCAN + 255) / 256, 256, 0, stream>>>(row_ptr, cursor, bsum);
  fill_pack<<<FILL_BLOCKS + 32, 256, 0, stream>>>(src_idx, dst_idx, cursor, src_perm,
                                                  Wa2, Wb2, BaH, BaL, BbH, BbL);

  int node_wave_blocks = NP / 4;   // wave per node, 4 waves/block

  // ---- layer a: h1 = xp @ Wa2 (bf16, fused dots), fused softmax+agg+relu (bf16) ----
  gemm_mfma<F, H, true><<<NP / 16, 256, 0, stream>>>(xp, BaH, BaL, h1b, asa, ada, sb, db);
  agg_a<<<node_wave_blocks, 256, 0, stream>>>(h1b, src_perm, row_ptr, sb, db, ba, hpb);

  // ---- layer b: h2 = hp @ Wb2 (bf16, fused dots), fused softmax+agg+head ----
  gemm_mfma<H, F, false><<<NP / 16, 256, 0, stream>>>(hpb, BbH, BbL, h2b, asb, adb, sb, db);
  agg_b<<<node_wave_blocks, 256, 0, stream>>>(h2b, src_perm, row_ptr, sb, db, bb, Wout, u, v);

  // ---- link-prediction head ----
  out_kernel<<<(NPAIR + 255) / 256, 256, 0, stream>>>(mask, u, v, bout, out);
}

// Round 9
// 344.934 us; speedup vs baseline: 2.2413x; 1.0839x over previous
//
#include <hip/hip_runtime.h>
#include <hip/hip_bf16.h>
#include <math.h>

#define NP 50000
#define F 128
#define H 256
#define E_PPI 800000
#define ET (E_PPI + NP)   // edges + self loops
#define NPAIR 200000
#define NSCAN (NP + 1)
#define NB_SCAN ((NSCAN + 1023) / 1024)   // 49
#define FILL_BLOCKS ((ET + 255) / 256)

typedef __attribute__((ext_vector_type(8))) short short8v;
typedef __attribute__((ext_vector_type(4))) float float4v;
typedef __attribute__((ext_vector_type(2))) float float2v;
typedef __attribute__((ext_vector_type(4))) unsigned int uint4v;

__device__ __forceinline__ short f2bs(float f) {  // f32 -> bf16 bits, RNE
  unsigned u = __builtin_bit_cast(unsigned, f);
  unsigned r = (u + 0x7FFFu + ((u >> 16) & 1u)) >> 16;
  return (short)r;
}
__device__ __forceinline__ float bs2f(short s) {
  unsigned u = ((unsigned)(unsigned short)s) << 16;
  return __builtin_bit_cast(float, u);
}
__device__ __forceinline__ float lrelu(float t) { return (t > 0.f) ? t : 0.2f * t; }

__device__ __forceinline__ float2v bf2x2(unsigned d) {
  float2v f;
  f.x = __builtin_bit_cast(float, d << 16);
  f.y = __builtin_bit_cast(float, d & 0xFFFF0000u);
  return f;
}
__device__ __forceinline__ float2v pkfma(float2v a, float2v b, float2v c) {
#if __has_builtin(__builtin_elementwise_fma)
  return __builtin_elementwise_fma(a, b, c);
#else
  float2v r; r.x = fmaf(a.x, b.x, c.x); r.y = fmaf(a.y, b.y, c.y); return r;
#endif
}

// ---------------- CSR build ----------------

__global__ void deg_kernel(const int* __restrict__ dst_idx, int* __restrict__ deg) {
  int k = blockIdx.x * blockDim.x + threadIdx.x;
  if (k >= ET) return;
  int d = (k < E_PPI) ? dst_idx[k] : (k - E_PPI);
  atomicAdd(&deg[d], 1);
}

__global__ void scan_partial(const int* __restrict__ deg, int* __restrict__ row_ptr,
                             int* __restrict__ bsum) {
  __shared__ int buf[1024];
  int tid = threadIdx.x;
  int idx = blockIdx.x * 1024 + tid;
  int v = (idx < NSCAN) ? deg[idx] : 0;   // deg[NP] stays 0
  buf[tid] = v;
  __syncthreads();
  for (int off = 1; off < 1024; off <<= 1) {
    int t = (tid >= off) ? buf[tid - off] : 0;
    __syncthreads();
    buf[tid] += t;
    __syncthreads();
  }
  if (idx < NSCAN) row_ptr[idx] = buf[tid] - v;     // exclusive within block
  if (tid == 1023) bsum[blockIdx.x] = buf[1023];
}

__global__ void scan_add(int* __restrict__ row_ptr, int* __restrict__ cursor,
                         const int* __restrict__ bsum) {
  __shared__ int soff[64];
  int tid = threadIdx.x;
  if (tid < 64) {
    int v = (tid < NB_SCAN) ? bsum[tid] : 0;
    for (int off = 1; off < 64; off <<= 1) {
      int t = __shfl_up(v, off);
      if (tid >= off) v += t;
    }
    int ex = __shfl_up(v, 1);
    if (tid == 0) ex = 0;
    soff[tid] = ex;
  }
  __syncthreads();
  int idx = blockIdx.x * blockDim.x + tid;
  if (idx >= NSCAN) return;
  int v = row_ptr[idx] + soff[idx >> 10];
  row_ptr[idx] = v;
  if (idx < NP) cursor[idx] = v;
}

// ---------------- weight pack into MFMA fragment order (bf16, hi only) ----------------

template<int K, int N>
__device__ __forceinline__ void pack_one(const float* __restrict__ B, short* __restrict__ Bp,
                                         int idx) {
  constexpr int KB = K / 32;
  int lane = idx & 63;
  int rest = idx >> 6;
  int kb = rest % KB;
  int tile = rest / KB;
  int n = tile * 16 + (lane & 15);
  int k0 = kb * 32 + (lane >> 4) * 8;
  size_t base = (size_t)idx * 8;
#pragma unroll
  for (int j = 0; j < 8; ++j) Bp[base + j] = f2bs(B[(size_t)(k0 + j) * N + n]);
}

// fused: CSR fill + both weight packs + head bias constants
__global__ void fill_pack(const int* __restrict__ src_idx, const int* __restrict__ dst_idx,
                          int* __restrict__ cursor, int* __restrict__ src_perm,
                          const float* __restrict__ Wa, const float* __restrict__ Wb,
                          short* __restrict__ BaP, short* __restrict__ BbP,
                          const float* __restrict__ bb, const float* __restrict__ Wout,
                          float* __restrict__ consts) {
  int b = blockIdx.x;
  if (b < FILL_BLOCKS) {
    int k = b * 256 + threadIdx.x;
    if (k >= ET) return;
    int s, d;
    if (k < E_PPI) { s = src_idx[k]; d = dst_idx[k]; }
    else           { s = d = k - E_PPI; }
    int pos = atomicAdd(&cursor[d], 1);
    src_perm[pos] = s;
  } else if (b < FILL_BLOCKS + 32) {
    int idx = (b - FILL_BLOCKS) * 256 + threadIdx.x;
    if (idx < 4096)      pack_one<F, H>(Wa, BaP, idx);          // 16 tiles * 4 kb * 64
    else                 pack_one<H, F>(Wb, BbP, idx - 4096);   // 8 tiles * 8 kb * 64
  } else {
    // consts: c1 = bb . Wout[:128], c2 = bb . Wout[128:]
    int lane = threadIdx.x;
    if (lane >= 64) return;
    float b0 = bb[lane], b1 = bb[lane + 64];
    float c1 = fmaf(b0, Wout[lane], b1 * Wout[lane + 64]);
    float c2 = fmaf(b0, Wout[128 + lane], b1 * Wout[192 + lane]);
#pragma unroll
    for (int o = 32; o; o >>= 1) {
      c1 += __shfl_xor(c1, o);
      c2 += __shfl_xor(c2, o);
    }
    if (lane == 0) { consts[0] = c1; consts[1] = c2; }
  }
}

// ---------------- MFMA GEMM + fused per-row dots ----------------
// AF32: convert A f32 rows to bf16 in-kernel. HEAD: also compute p = row.W1,
// q = row.W2 from f32 accumulators and skip the C store (layer b: C is dead).

template<int K, int N, bool AF32, bool HEAD>
__launch_bounds__(256)
__global__ void gemm_mfma(const void* __restrict__ Av, const short* __restrict__ Bp,
                          short* __restrict__ Cb, const float* __restrict__ a_s,
                          const float* __restrict__ a_d, const float* __restrict__ W1,
                          const float* __restrict__ W2, float* __restrict__ sb,
                          float* __restrict__ db, float2v* __restrict__ pq) {
  constexpr int KB = K / 32;
  constexpr int TPW = N / 64;   // 16-col tiles per wave
  __shared__ float sred[4][16];
  __shared__ float dred[4][16];
  __shared__ float pred[4][16];
  __shared__ float qred[4][16];
  int lane = threadIdx.x & 63, wave = threadIdx.x >> 6;
  int ln16 = lane & 15, quad = lane >> 4;
  int m0 = blockIdx.x * 16;
  float4v acc[TPW];
#pragma unroll
  for (int t = 0; t < TPW; ++t) acc[t] = (float4v)0.f;
#pragma unroll
  for (int kb = 0; kb < KB; ++kb) {
    int ka = kb * 32 + quad * 8;
    short8v ah;
    if constexpr (AF32) {
      const float* ap = (const float*)Av + (size_t)(m0 + ln16) * K + ka;
      float4v a0 = *(const float4v*)ap;
      float4v a1 = *(const float4v*)(ap + 4);
#pragma unroll
      for (int j = 0; j < 4; ++j) { ah[j] = f2bs(a0[j]); ah[4 + j] = f2bs(a1[j]); }
    } else {
      ah = *(const short8v*)((const short*)Av + (size_t)(m0 + ln16) * K + ka);
    }
#pragma unroll
    for (int t = 0; t < TPW; ++t) {
      int tile = wave * TPW + t;
      short8v bh = *(const short8v*)(Bp + ((size_t)(tile * KB + kb) * 64 + lane) * 8);
      acc[t] = __builtin_amdgcn_mfma_f32_16x16x32_bf16(ah, bh, acc[t], 0, 0, 0);
    }
  }
  // store h (bf16) unless HEAD; C/D layout: col = lane&15, row = quad*4 + reg
  if constexpr (!HEAD) {
#pragma unroll
    for (int t = 0; t < TPW; ++t) {
      int cc = (wave * TPW + t) * 16 + ln16;
#pragma unroll
      for (int r = 0; r < 4; ++r) {
        int rr = m0 + quad * 4 + r;
        Cb[(size_t)rr * N + cc] = f2bs(acc[t][r]);
      }
    }
  }
  // fused per-row dots over this wave's columns (f32 accs)
  float su[4] = {0.f, 0.f, 0.f, 0.f}, dv[4] = {0.f, 0.f, 0.f, 0.f};
  float pu[4] = {0.f, 0.f, 0.f, 0.f}, qv[4] = {0.f, 0.f, 0.f, 0.f};
#pragma unroll
  for (int t = 0; t < TPW; ++t) {
    int cc = (wave * TPW + t) * 16 + ln16;
    float as = a_s[cc], ad = a_d[cc];
    float w1 = HEAD ? W1[cc] : 0.f, w2 = HEAD ? W2[cc] : 0.f;
#pragma unroll
    for (int r = 0; r < 4; ++r) {
      su[r] = fmaf(acc[t][r], as, su[r]);
      dv[r] = fmaf(acc[t][r], ad, dv[r]);
      if constexpr (HEAD) {
        pu[r] = fmaf(acc[t][r], w1, pu[r]);
        qv[r] = fmaf(acc[t][r], w2, qv[r]);
      }
    }
  }
#pragma unroll
  for (int r = 0; r < 4; ++r) {
    for (int off = 1; off < 16; off <<= 1) {
      su[r] += __shfl_xor(su[r], off);
      dv[r] += __shfl_xor(dv[r], off);
      if constexpr (HEAD) {
        pu[r] += __shfl_xor(pu[r], off);
        qv[r] += __shfl_xor(qv[r], off);
      }
    }
  }
  if (ln16 == 0) {
#pragma unroll
    for (int r = 0; r < 4; ++r) {
      sred[wave][quad * 4 + r] = su[r];
      dred[wave][quad * 4 + r] = dv[r];
      if constexpr (HEAD) {
        pred[wave][quad * 4 + r] = pu[r];
        qred[wave][quad * 4 + r] = qv[r];
      }
    }
  }
  __syncthreads();
  if (threadIdx.x < 16) {
    int row = threadIdx.x;
    sb[m0 + row] = sred[0][row] + sred[1][row] + sred[2][row] + sred[3][row];
    db[m0 + row] = dred[0][row] + dred[1][row] + dred[2][row] + dred[3][row];
    if constexpr (HEAD) {
      float2v t;
      t.x = pred[0][row] + pred[1][row] + pred[2][row] + pred[3][row];
      t.y = qred[0][row] + qred[1][row] + qred[2][row] + qred[3][row];
      pq[m0 + row] = t;
    }
  }
}

// ---------------- fused softmax + aggregation, layer a (unchanged from R8) ----------------

__launch_bounds__(256)
__global__ void agg_a(const short* __restrict__ h, const int* __restrict__ src_perm,
                      const int* __restrict__ row_ptr, const float* __restrict__ sb,
                      const float* __restrict__ db, const float* __restrict__ bias,
                      short* __restrict__ outb) {
  int gid = blockIdx.x * blockDim.x + threadIdx.x;
  int dst = gid >> 6, lane = gid & 63;
  if (dst >= NP) return;
  int half = lane >> 5, l32 = lane & 31;
  int s = row_ptr[dst], deg = row_ptr[dst + 1] - s;
  float di = db[dst];
  // phase 1: lane-parallel online softmax
  float m = -1e30f, ssum = 0.f, x0 = -1e30f;
  for (int c0 = 0; c0 < deg; c0 += 64) {
    int idx = c0 + lane;
    float x = -1e30f;
    if (idx < deg) x = lrelu(sb[src_perm[s + idx]] + di);
    if (c0 == 0) x0 = x;
    float cm = x;
#pragma unroll
    for (int o = 32; o; o >>= 1) cm = fmaxf(cm, __shfl_xor(cm, o));
    float nm = fmaxf(m, cm);
    float ex = (idx < deg) ? __expf(x - nm) : 0.f;
#pragma unroll
    for (int o = 32; o; o >>= 1) ex += __shfl_xor(ex, o);
    ssum = ssum * __expf(m - nm) + ex;
    m = nm;
  }
  float inv = 1.0f / ssum;
  float w0 = __expf(x0 - m);   // lane i -> unnormalized weight of edge i
  // phase 2: 2 edges/iter (half-wave, 16B/lane), unroll x2, packed fma
  float2v acc2[4];
#pragma unroll
  for (int k = 0; k < 4; ++k) acc2[k] = (float2v)0.f;
  for (int it0 = 0; it0 < deg; it0 += 4) {
    int e1 = it0 + half, e2 = it0 + 2 + half;
    bool v1 = (e1 < deg), v2 = (e2 < deg);
    int s1 = v1 ? src_perm[s + e1] : src_perm[s];
    int s2 = v2 ? src_perm[s + e2] : src_perm[s];
    short8v xa = *(const short8v*)(h + (size_t)s1 * 256 + l32 * 8);
    short8v xb = *(const short8v*)(h + (size_t)s2 * 256 + l32 * 8);
    float w1 = __shfl(w0, e1 & 63);
    float w2 = __shfl(w0, e2 & 63);
    if (deg > 64) {   // wave-uniform
      if (e1 >= 64 && v1) w1 = __expf(lrelu(sb[s1] + di) - m);
      if (e2 >= 64 && v2) w2 = __expf(lrelu(sb[s2] + di) - m);
    }
    w1 = v1 ? w1 : 0.f;
    w2 = v2 ? w2 : 0.f;
    uint4v da = __builtin_bit_cast(uint4v, xa);
    uint4v dbv = __builtin_bit_cast(uint4v, xb);
    float2v W1 = {w1, w1}, W2 = {w2, w2};
#pragma unroll
    for (int k = 0; k < 4; ++k) {
      acc2[k] = pkfma(bf2x2(da[k]), W1, acc2[k]);
      acc2[k] = pkfma(bf2x2(dbv[k]), W2, acc2[k]);
    }
  }
#pragma unroll
  for (int k = 0; k < 4; ++k) {
    acc2[k].x += __shfl_xor(acc2[k].x, 32);
    acc2[k].y += __shfl_xor(acc2[k].y, 32);
  }
  if (half == 0) {
    short8v o;
#pragma unroll
    for (int k = 0; k < 4; ++k) {
      o[2 * k]     = f2bs(fmaxf(fmaf(acc2[k].x, inv, bias[l32 * 8 + 2 * k]),     0.f));
      o[2 * k + 1] = f2bs(fmaxf(fmaf(acc2[k].y, inv, bias[l32 * 8 + 2 * k + 1]), 0.f));
    }
    *(short8v*)(outb + (size_t)dst * 256 + l32 * 8) = o;
  }
}

// ---------------- layer-b softmax + scalar aggregation (head collapsed) ----------------
// u[dst] = sum_j alpha_j p[src_j], v[dst] = sum_j alpha_j q[src_j].
// Flash-style single pass; 8B gathers from L2-resident pq (400 KB).

__launch_bounds__(256)
__global__ void agg_uv(const int* __restrict__ src_perm, const int* __restrict__ row_ptr,
                       const float* __restrict__ sb, const float* __restrict__ db,
                       const float2v* __restrict__ pq, float* __restrict__ u,
                       float* __restrict__ v_out) {
  int gid = blockIdx.x * blockDim.x + threadIdx.x;
  int dst = gid >> 6, lane = gid & 63;
  if (dst >= NP) return;
  int s = row_ptr[dst], deg = row_ptr[dst + 1] - s;
  float di = db[dst];
  float m = -1e30f, ssum = 0.f, uacc = 0.f, vacc = 0.f;
  for (int c0 = 0; c0 < deg; c0 += 64) {
    int idx = c0 + lane;
    bool val = idx < deg;
    int src = val ? src_perm[s + idx] : src_perm[s];
    float x = val ? lrelu(sb[src] + di) : -1e30f;
    float2v pqv = pq[src];
    float cm = x;
#pragma unroll
    for (int o = 32; o; o >>= 1) cm = fmaxf(cm, __shfl_xor(cm, o));
    float nm = fmaxf(m, cm);
    float scale = __expf(m - nm);
    float ex = val ? __expf(x - nm) : 0.f;
    float eu = ex * pqv.x, ev = ex * pqv.y;
#pragma unroll
    for (int o = 32; o; o >>= 1) {
      ex += __shfl_xor(ex, o);
      eu += __shfl_xor(eu, o);
      ev += __shfl_xor(ev, o);
    }
    ssum = ssum * scale + ex;
    uacc = uacc * scale + eu;
    vacc = vacc * scale + ev;
    m = nm;
  }
  if (lane == 0) {
    float inv = 1.0f / ssum;
    u[dst] = uacc * inv;
    v_out[dst] = vacc * inv;
  }
}

// ---------------- output ----------------

__global__ void out_kernel(const int* __restrict__ mask, const float* __restrict__ u,
                           const float* __restrict__ v, const float* __restrict__ bout,
                           const float* __restrict__ consts, float* __restrict__ out) {
  int p = blockIdx.x * blockDim.x + threadIdx.x;
  if (p >= NPAIR) return;
  int a = mask[2 * p], b = mask[2 * p + 1];
  float logit = u[a] + v[b] + bout[0] + consts[0] + consts[1];
  out[p] = 1.0f / (1.0f + __expf(-logit));
}

// ---------------- launch ----------------

extern "C" void kernel_launch(void* const* d_in, const int* in_sizes, int n_in,
                              void* d_out, int out_size, void* d_ws, size_t ws_size,
                              hipStream_t stream) {
  const float* xp   = (const float*)d_in[0];
  const int*   ei   = (const int*)d_in[5];          // ei_ppi (2, E_PPI)
  const int*   mask = (const int*)d_in[6];
  const float* Wa2  = (const float*)d_in[7]  + 2 * F * H;   // Wa[2]  [128,256]
  const float* asa  = (const float*)d_in[8]  + 2 * H;
  const float* ada  = (const float*)d_in[9]  + 2 * H;
  const float* ba   = (const float*)d_in[10] + 2 * H;
  const float* Wb2  = (const float*)d_in[11] + 2 * H * F;   // Wb[2]  [256,128]
  const float* asb  = (const float*)d_in[12] + 2 * F;
  const float* adb  = (const float*)d_in[13] + 2 * F;
  const float* bb   = (const float*)d_in[14] + 2 * F;
  const float* Wout = (const float*)d_in[21];
  const float* bout = (const float*)d_in[22];
  float* out = (float*)d_out;

  char* ws = (char*)d_ws;
  size_t off = 0;
  auto alloc = [&](size_t bytes) {
    void* p = ws + off;
    off = (off + bytes + 255) & ~(size_t)255;
    return p;
  };
  short* h1b     = (short*)alloc((size_t)NP * H * 2);      // bf16 [50000,256]
  short* hpb     = (short*)alloc((size_t)NP * H * 2);      // bf16 relu'd layer-a out
  int*   src_perm= (int*)alloc((size_t)ET * 4);
  int*   row_ptr = (int*)alloc((size_t)NSCAN * 4);
  int*   cursor  = (int*)alloc((size_t)NP * 4);
  int*   deg     = (int*)alloc((size_t)NSCAN * 4);
  int*   bsum    = (int*)alloc((size_t)NB_SCAN * 4);
  float* sb      = (float*)alloc((size_t)NP * 4);
  float* db      = (float*)alloc((size_t)NP * 4);
  float2v* pq    = (float2v*)alloc((size_t)NP * 8);
  float* u       = (float*)alloc((size_t)NP * 4);
  float* v       = (float*)alloc((size_t)NP * 4);
  short* BaP     = (short*)alloc((size_t)F * H * 2);       // packed Wa2
  short* BbP     = (short*)alloc((size_t)H * F * 2);       // packed Wb2
  float* consts  = (float*)alloc(2 * 4);

  const int* src_idx = ei;
  const int* dst_idx = ei + E_PPI;

  // CSR over ppi edges + self loops (shared by both layers)
  hipMemsetAsync(deg, 0, (size_t)NSCAN * 4, stream);
  deg_kernel<<<(ET + 255) / 256, 256, 0, stream>>>(dst_idx, deg);
  scan_partial<<<NB_SCAN, 1024, 0, stream>>>(deg, row_ptr, bsum);
  scan_add<<<(NSCAN + 255) / 256, 256, 0, stream>>>(row_ptr, cursor, bsum);
  fill_pack<<<FILL_BLOCKS + 33, 256, 0, stream>>>(src_idx, dst_idx, cursor, src_perm,
                                                  Wa2, Wb2, BaP, BbP, bb, Wout, consts);

  int node_wave_blocks = NP / 4;   // wave per node, 4 waves/block

  // ---- layer a: h1 = xp @ Wa2 (bf16, fused dots), fused softmax+agg+relu (bf16) ----
  gemm_mfma<F, H, true, false><<<NP / 16, 256, 0, stream>>>(
      xp, BaP, h1b, asa, ada, nullptr, nullptr, sb, db, nullptr);
  agg_a<<<node_wave_blocks, 256, 0, stream>>>(h1b, src_perm, row_ptr, sb, db, ba, hpb);

  // ---- layer b: dots only (sb, db, p, q) — h2 itself is dead ----
  gemm_mfma<H, F, false, true><<<NP / 16, 256, 0, stream>>>(
      hpb, BbP, nullptr, asb, adb, Wout, Wout + F, sb, db, pq);
  agg_uv<<<node_wave_blocks, 256, 0, stream>>>(src_perm, row_ptr, sb, db, pq, u, v);

  // ---- link-prediction head ----
  out_kernel<<<(NPAIR + 255) / 256, 256, 0, stream>>>(mask, u, v, bout, consts, out);
}